// Round 1
// baseline (978.988 us; speedup 1.0000x reference)
//
#include <hip/hip_runtime.h>
#include <math.h>

#define N_ 32
#define T_ 2048
#define E_ 512
#define D_ 1024
#define U_ 256

// ---------------- kernel 1: proj_q = queries @ W_q (partials over d-chunks) ----------------
__global__ __launch_bounds__(256) void projq_partial_kernel(
    const float* __restrict__ queries, const float* __restrict__ W_q,
    float* __restrict__ pq_part) {
  const int b = blockIdx.y, ch = blockIdx.x, tid = threadIdx.x;
  const int d0 = ch * 64;
  const float* q = queries + b * D_ + d0;
  const float* wq = W_q + (size_t)d0 * U_ + tid;
  float acc = 0.f;
#pragma unroll
  for (int d = 0; d < 64; ++d)
    acc = fmaf(q[d], wq[(size_t)d * U_], acc);
  pq_part[((b * 16) + ch) * U_ + tid] = acc;
}

__global__ __launch_bounds__(256) void projq_reduce_kernel(
    const float* __restrict__ pq_part, float* __restrict__ proj_q) {
  const int b = blockIdx.x, tid = threadIdx.x;
  float s = 0.f;
#pragma unroll
  for (int c = 0; c < 16; ++c) s += pq_part[((b * 16) + c) * U_ + tid];
  proj_q[b * U_ + tid] = s;
}

// ---------------- kernel 2: fused score GEMM + tanh/v reduce + sigmoid ----------------
// WG: 256 threads = 4 waves. Tile: 64 t-rows x 256 u-cols. Thread (tx,ty):
// tx=lane covers u-quad tx*4..tx*4+3, ty=wave covers t rows ty*16..ty*16+15.
#define TT 64
#define EC 32

__global__ __launch_bounds__(256, 4) void score_kernel(
    const float* __restrict__ memory, const float* __restrict__ W_k,
    const float* __restrict__ proj_q, const float* __restrict__ v,
    float* __restrict__ p_choose) {
  __shared__ float smem[TT][EC];   // 8 KB memory tile
  __shared__ float swk[EC][U_];    // 32 KB W_k chunk
  const int b = blockIdx.y;
  const int t0 = blockIdx.x * TT;
  const int tid = threadIdx.x;
  const int tx = tid & 63;
  const int ty = tid >> 6;

  float acc[16][4];
#pragma unroll
  for (int i = 0; i < 16; ++i)
#pragma unroll
    for (int j = 0; j < 4; ++j) acc[i][j] = 0.f;

  const int mr = tid >> 2;        // 0..63 (t row within tile)
  const int mc = (tid & 3) * 8;   // 0,8,16,24 (e col within chunk)

  for (int ec = 0; ec < E_; ec += EC) {
    // issue global loads first (overlap with previous compute)
    const float* msrc = memory + ((size_t)(b * T_ + t0 + mr)) * E_ + ec + mc;
    float4 a0 = *(const float4*)(msrc);
    float4 a1 = *(const float4*)(msrc + 4);
    float4 wrow[8];
#pragma unroll
    for (int q = 0; q < 8; ++q) {
      const int r = q * 4 + ty;
      wrow[q] = *(const float4*)(W_k + (size_t)(ec + r) * U_ + tx * 4);
    }
    __syncthreads();  // previous iteration's readers done before overwrite
    *(float4*)&smem[mr][mc] = a0;
    *(float4*)&smem[mr][mc + 4] = a1;
#pragma unroll
    for (int q = 0; q < 8; ++q)
      *(float4*)&swk[q * 4 + ty][tx * 4] = wrow[q];
    __syncthreads();

#pragma unroll
    for (int eq = 0; eq < EC; eq += 4) {
      float4 w0 = *(const float4*)&swk[eq + 0][tx * 4];
      float4 w1 = *(const float4*)&swk[eq + 1][tx * 4];
      float4 w2 = *(const float4*)&swk[eq + 2][tx * 4];
      float4 w3 = *(const float4*)&swk[eq + 3][tx * 4];
#pragma unroll
      for (int i = 0; i < 16; ++i) {
        float4 m = *(const float4*)&smem[ty * 16 + i][eq];  // broadcast read
        acc[i][0] = fmaf(m.x, w0.x, acc[i][0]); acc[i][0] = fmaf(m.y, w1.x, acc[i][0]);
        acc[i][0] = fmaf(m.z, w2.x, acc[i][0]); acc[i][0] = fmaf(m.w, w3.x, acc[i][0]);
        acc[i][1] = fmaf(m.x, w0.y, acc[i][1]); acc[i][1] = fmaf(m.y, w1.y, acc[i][1]);
        acc[i][1] = fmaf(m.z, w2.y, acc[i][1]); acc[i][1] = fmaf(m.w, w3.y, acc[i][1]);
        acc[i][2] = fmaf(m.x, w0.z, acc[i][2]); acc[i][2] = fmaf(m.y, w1.z, acc[i][2]);
        acc[i][2] = fmaf(m.z, w2.z, acc[i][2]); acc[i][2] = fmaf(m.w, w3.z, acc[i][2]);
        acc[i][3] = fmaf(m.x, w0.w, acc[i][3]); acc[i][3] = fmaf(m.y, w1.w, acc[i][3]);
        acc[i][3] = fmaf(m.z, w2.w, acc[i][3]); acc[i][3] = fmaf(m.w, w3.w, acc[i][3]);
      }
    }
  }

  // epilogue: weights[t] = sum_u tanh(pq[u]+pk[t][u]) * v[u]; p = sigmoid(w)
  float4 pq = *(const float4*)(proj_q + b * U_ + tx * 4);
  float4 vv = *(const float4*)(v + tx * 4);
#pragma unroll
  for (int i = 0; i < 16; ++i) {
    float w = tanhf(pq.x + acc[i][0]) * vv.x + tanhf(pq.y + acc[i][1]) * vv.y +
              tanhf(pq.z + acc[i][2]) * vv.z + tanhf(pq.w + acc[i][3]) * vv.w;
#pragma unroll
    for (int off = 32; off > 0; off >>= 1) w += __shfl_xor(w, off, 64);
    if (tx == 0) p_choose[b * T_ + t0 + ty * 16 + i] = 1.0f / (1.0f + expf(-w));
  }
}

// ---------------- kernel 3: monotonic-attention scan per batch row ----------------
__device__ __forceinline__ float block_incl_scan(float val, float* sbuf, int tid) {
  float x = val;
  sbuf[tid] = x;
  __syncthreads();
#pragma unroll
  for (int off = 1; off < 256; off <<= 1) {
    float t = (tid >= off) ? sbuf[tid - off] : 0.f;
    __syncthreads();
    x += t;
    sbuf[tid] = x;
    __syncthreads();
  }
  return x;  // inclusive prefix over 256 thread values
}

__global__ __launch_bounds__(256) void scan_kernel(
    const float* __restrict__ p_choose, const float* __restrict__ prev,
    float* __restrict__ align_out) {
  __shared__ float sbuf[256];
  const int b = blockIdx.x, tid = threadIdx.x;
  const int base = b * T_ + tid * 8;
  float4 p0 = *(const float4*)(p_choose + base);
  float4 p1 = *(const float4*)(p_choose + base + 4);
  float p[8] = {p0.x, p0.y, p0.z, p0.w, p1.x, p1.y, p1.z, p1.w};
  float s[8];
  float run = 0.f;
#pragma unroll
  for (int k = 0; k < 8; ++k) {
    float x = 1.0f - p[k];
    x = fminf(fmaxf(x, 1e-20f), 1.0f);
    run += logf(x);
    s[k] = run;  // local inclusive logsum
  }
  float incl = block_incl_scan(run, sbuf, tid);
  float excl = incl - run;  // sum of preceding threads' chunks
  float cp[8];              // exclusive cumprod(1-p) = exp(exclusive logsum)
#pragma unroll
  for (int k = 0; k < 8; ++k)
    cp[k] = expf(excl + (k ? s[k - 1] : 0.f));
  float4 r0 = *(const float4*)(prev + base);
  float4 r1 = *(const float4*)(prev + base + 4);
  float pr[8] = {r0.x, r0.y, r0.z, r0.w, r1.x, r1.y, r1.z, r1.w};
  float s2[8];
  float run2 = 0.f;
#pragma unroll
  for (int k = 0; k < 8; ++k) {
    float d = fminf(fmaxf(cp[k], 1e-10f), 1.0f);
    run2 += pr[k] / d;
    s2[k] = run2;
  }
  float incl2 = block_incl_scan(run2, sbuf, tid);
  float excl2 = incl2 - run2;
#pragma unroll
  for (int k = 0; k < 8; ++k)
    p[k] = p[k] * cp[k] * (excl2 + s2[k]);  // alignments
  *(float4*)(align_out + base) = make_float4(p[0], p[1], p[2], p[3]);
  *(float4*)(align_out + base + 4) = make_float4(p[4], p[5], p[6], p[7]);
}

// ---------------- kernel 4/5: contexts = alignments . memory ----------------
__global__ __launch_bounds__(256) void ctx_partial_kernel(
    const float* __restrict__ memory, const float* __restrict__ align,
    float* __restrict__ partials) {
  const int b = blockIdx.y, ch = blockIdx.x, tid = threadIdx.x;
  const int t0 = ch * 128;
  const float* mrow = memory + ((size_t)(b * T_ + t0)) * E_ + tid * 2;
  const float* arow = align + b * T_ + t0;
  float a0 = 0.f, a1 = 0.f;
#pragma unroll 8
  for (int t = 0; t < 128; ++t) {
    float a = arow[t];  // wave-uniform -> scalar load
    float2 m = *(const float2*)(mrow + (size_t)t * E_);
    a0 = fmaf(a, m.x, a0);
    a1 = fmaf(a, m.y, a1);
  }
  *(float2*)(partials + ((size_t)(b * 16 + ch)) * E_ + tid * 2) = make_float2(a0, a1);
}

__global__ __launch_bounds__(256) void ctx_reduce_kernel(
    const float* __restrict__ partials, float* __restrict__ ctx) {
  const int b = blockIdx.x, tid = threadIdx.x;
#pragma unroll
  for (int e = tid; e < E_; e += 256) {
    float s = 0.f;
#pragma unroll
    for (int c = 0; c < 16; ++c) s += partials[((size_t)(b * 16 + c)) * E_ + e];
    ctx[b * E_ + e] = s;
  }
}

// ---------------- launch ----------------
extern "C" void kernel_launch(void* const* d_in, const int* in_sizes, int n_in,
                              void* d_out, int out_size, void* d_ws, size_t ws_size,
                              hipStream_t stream) {
  (void)in_sizes; (void)n_in; (void)out_size; (void)ws_size;
  const float* queries = (const float*)d_in[0];
  const float* prev    = (const float*)d_in[1];
  const float* memory  = (const float*)d_in[2];
  const float* W_q     = (const float*)d_in[3];
  const float* W_k     = (const float*)d_in[4];
  const float* v       = (const float*)d_in[5];

  float* out = (float*)d_out;
  float* ctx_out = out;              // [N,E]
  float* align_out = out + N_ * E_;  // [N,T]

  // ws layout (floats), with lifetime-based overlap (peak 262144 floats = 1 MiB):
  //   pq_part   [0      .. 131072)   dead after projq_reduce
  //   p_choose  [131072 .. 196608)   dead after scan
  //   proj_q    [196608 .. 204800)   dead after score
  //   ctx_parts [0      .. 262144)   live only after scan
  float* ws = (float*)d_ws;
  float* pq_part   = ws;
  float* p_choose  = ws + 131072;
  float* proj_q    = ws + 196608;
  float* ctx_parts = ws;

  projq_partial_kernel<<<dim3(16, N_), 256, 0, stream>>>(queries, W_q, pq_part);
  projq_reduce_kernel<<<dim3(N_), 256, 0, stream>>>(pq_part, proj_q);
  score_kernel<<<dim3(T_ / TT, N_), 256, 0, stream>>>(memory, W_k, proj_q, v, p_choose);
  scan_kernel<<<dim3(N_), 256, 0, stream>>>(p_choose, prev, align_out);
  ctx_partial_kernel<<<dim3(16, N_), 256, 0, stream>>>(memory, align_out, ctx_parts);
  ctx_reduce_kernel<<<dim3(N_), 256, 0, stream>>>(ctx_parts, ctx_out);
}

// Round 2
// 466.144 us; speedup vs baseline: 2.1002x; 2.1002x over previous
//
#include <hip/hip_runtime.h>
#include <math.h>

#define N_ 32
#define T_ 2048
#define E_ 512
#define D_ 1024
#define U_ 256

// ---------------- kernel 1: proj_q = queries @ W_q (partials over d-chunks) ----------------
__global__ __launch_bounds__(256) void projq_partial_kernel(
    const float* __restrict__ queries, const float* __restrict__ W_q,
    float* __restrict__ pq_part) {
  const int b = blockIdx.y, ch = blockIdx.x, tid = threadIdx.x;
  const int d0 = ch * 64;
  const float* q = queries + b * D_ + d0;
  const float* wq = W_q + (size_t)d0 * U_ + tid;
  float acc = 0.f;
#pragma unroll
  for (int d = 0; d < 64; ++d)
    acc = fmaf(q[d], wq[(size_t)d * U_], acc);
  pq_part[((b * 16) + ch) * U_ + tid] = acc;
}

__global__ __launch_bounds__(256) void projq_reduce_kernel(
    const float* __restrict__ pq_part, float* __restrict__ proj_q) {
  const int b = blockIdx.x, tid = threadIdx.x;
  float s = 0.f;
#pragma unroll
  for (int c = 0; c < 16; ++c) s += pq_part[((b * 16) + c) * U_ + tid];
  proj_q[b * U_ + tid] = s;
}

// ---------------- kernel 2: fused score GEMM + tanh/v reduce + sigmoid ----------------
// WG: 256 threads = 4 waves. Tile: 64 t-rows x 256 u-cols. Thread (tx,ty):
// tx=lane covers u-quad tx*4..tx*4+3, ty=wave covers t rows ty*16..ty*16+15.
// NOTE: no min-occupancy clamp — __launch_bounds__(256,4) in R1 forced
// VGPR_Count=64 and spilled the 64-register accumulator tile to scratch
// (1.5 GB/dispatch of WRITE_SIZE). LDS (40 KB) caps occupancy at 4 blk/CU.
#define TT 64
#define EC 32

__global__ __launch_bounds__(256) void score_kernel(
    const float* __restrict__ memory, const float* __restrict__ W_k,
    const float* __restrict__ proj_q, const float* __restrict__ v,
    float* __restrict__ p_choose) {
  __shared__ float smem[TT][EC];   // 8 KB memory tile
  __shared__ float swk[EC][U_];    // 32 KB W_k chunk
  const int b = blockIdx.y;
  const int t0 = blockIdx.x * TT;
  const int tid = threadIdx.x;
  const int tx = tid & 63;
  const int ty = tid >> 6;

  float acc[16][4];
#pragma unroll
  for (int i = 0; i < 16; ++i)
#pragma unroll
    for (int j = 0; j < 4; ++j) acc[i][j] = 0.f;

  const int mr = tid >> 2;        // 0..63 (t row within tile)
  const int mc = (tid & 3) * 8;   // 0,8,16,24 (e col within chunk)

  for (int ec = 0; ec < E_; ec += EC) {
    // issue global loads first (overlap with previous compute)
    const float* msrc = memory + ((size_t)(b * T_ + t0 + mr)) * E_ + ec + mc;
    float4 a0 = *(const float4*)(msrc);
    float4 a1 = *(const float4*)(msrc + 4);
    float4 wrow[8];
#pragma unroll
    for (int q = 0; q < 8; ++q) {
      const int r = q * 4 + ty;
      wrow[q] = *(const float4*)(W_k + (size_t)(ec + r) * U_ + tx * 4);
    }
    __syncthreads();  // previous iteration's readers done before overwrite
    *(float4*)&smem[mr][mc] = a0;
    *(float4*)&smem[mr][mc + 4] = a1;
#pragma unroll
    for (int q = 0; q < 8; ++q)
      *(float4*)&swk[q * 4 + ty][tx * 4] = wrow[q];
    __syncthreads();

#pragma unroll
    for (int eq = 0; eq < EC; eq += 4) {
      float4 w0 = *(const float4*)&swk[eq + 0][tx * 4];
      float4 w1 = *(const float4*)&swk[eq + 1][tx * 4];
      float4 w2 = *(const float4*)&swk[eq + 2][tx * 4];
      float4 w3 = *(const float4*)&swk[eq + 3][tx * 4];
#pragma unroll
      for (int i = 0; i < 16; ++i) {
        float4 m = *(const float4*)&smem[ty * 16 + i][eq];  // broadcast read
        acc[i][0] = fmaf(m.x, w0.x, acc[i][0]); acc[i][0] = fmaf(m.y, w1.x, acc[i][0]);
        acc[i][0] = fmaf(m.z, w2.x, acc[i][0]); acc[i][0] = fmaf(m.w, w3.x, acc[i][0]);
        acc[i][1] = fmaf(m.x, w0.y, acc[i][1]); acc[i][1] = fmaf(m.y, w1.y, acc[i][1]);
        acc[i][1] = fmaf(m.z, w2.y, acc[i][1]); acc[i][1] = fmaf(m.w, w3.y, acc[i][1]);
        acc[i][2] = fmaf(m.x, w0.z, acc[i][2]); acc[i][2] = fmaf(m.y, w1.z, acc[i][2]);
        acc[i][2] = fmaf(m.z, w2.z, acc[i][2]); acc[i][2] = fmaf(m.w, w3.z, acc[i][2]);
        acc[i][3] = fmaf(m.x, w0.w, acc[i][3]); acc[i][3] = fmaf(m.y, w1.w, acc[i][3]);
        acc[i][3] = fmaf(m.z, w2.w, acc[i][3]); acc[i][3] = fmaf(m.w, w3.w, acc[i][3]);
      }
    }
  }

  // epilogue: weights[t] = sum_u tanh(pq[u]+pk[t][u]) * v[u]; p = sigmoid(w)
  float4 pq = *(const float4*)(proj_q + b * U_ + tx * 4);
  float4 vv = *(const float4*)(v + tx * 4);
#pragma unroll
  for (int i = 0; i < 16; ++i) {
    float w = tanhf(pq.x + acc[i][0]) * vv.x + tanhf(pq.y + acc[i][1]) * vv.y +
              tanhf(pq.z + acc[i][2]) * vv.z + tanhf(pq.w + acc[i][3]) * vv.w;
#pragma unroll
    for (int off = 32; off > 0; off >>= 1) w += __shfl_xor(w, off, 64);
    if (tx == 0) p_choose[b * T_ + t0 + ty * 16 + i] = 1.0f / (1.0f + expf(-w));
  }
}

// ---------------- kernel 3: monotonic-attention scan per batch row ----------------
__device__ __forceinline__ float block_incl_scan(float val, float* sbuf, int tid) {
  float x = val;
  sbuf[tid] = x;
  __syncthreads();
#pragma unroll
  for (int off = 1; off < 256; off <<= 1) {
    float t = (tid >= off) ? sbuf[tid - off] : 0.f;
    __syncthreads();
    x += t;
    sbuf[tid] = x;
    __syncthreads();
  }
  return x;  // inclusive prefix over 256 thread values
}

__global__ __launch_bounds__(256) void scan_kernel(
    const float* __restrict__ p_choose, const float* __restrict__ prev,
    float* __restrict__ align_out) {
  __shared__ float sbuf[256];
  const int b = blockIdx.x, tid = threadIdx.x;
  const int base = b * T_ + tid * 8;
  float4 p0 = *(const float4*)(p_choose + base);
  float4 p1 = *(const float4*)(p_choose + base + 4);
  float p[8] = {p0.x, p0.y, p0.z, p0.w, p1.x, p1.y, p1.z, p1.w};
  float s[8];
  float run = 0.f;
#pragma unroll
  for (int k = 0; k < 8; ++k) {
    float x = 1.0f - p[k];
    x = fminf(fmaxf(x, 1e-20f), 1.0f);
    run += logf(x);
    s[k] = run;  // local inclusive logsum
  }
  float incl = block_incl_scan(run, sbuf, tid);
  float excl = incl - run;  // sum of preceding threads' chunks
  float cp[8];              // exclusive cumprod(1-p) = exp(exclusive logsum)
#pragma unroll
  for (int k = 0; k < 8; ++k)
    cp[k] = expf(excl + (k ? s[k - 1] : 0.f));
  float4 r0 = *(const float4*)(prev + base);
  float4 r1 = *(const float4*)(prev + base + 4);
  float pr[8] = {r0.x, r0.y, r0.z, r0.w, r1.x, r1.y, r1.z, r1.w};
  float s2[8];
  float run2 = 0.f;
#pragma unroll
  for (int k = 0; k < 8; ++k) {
    float d = fminf(fmaxf(cp[k], 1e-10f), 1.0f);
    run2 += pr[k] / d;
    s2[k] = run2;
  }
  float incl2 = block_incl_scan(run2, sbuf, tid);
  float excl2 = incl2 - run2;
#pragma unroll
  for (int k = 0; k < 8; ++k)
    p[k] = p[k] * cp[k] * (excl2 + s2[k]);  // alignments
  *(float4*)(align_out + base) = make_float4(p[0], p[1], p[2], p[3]);
  *(float4*)(align_out + base + 4) = make_float4(p[4], p[5], p[6], p[7]);
}

// ---------------- kernel 4/5: contexts = alignments . memory ----------------
__global__ __launch_bounds__(256) void ctx_partial_kernel(
    const float* __restrict__ memory, const float* __restrict__ align,
    float* __restrict__ partials) {
  const int b = blockIdx.y, ch = blockIdx.x, tid = threadIdx.x;
  const int t0 = ch * 128;
  const float* mrow = memory + ((size_t)(b * T_ + t0)) * E_ + tid * 2;
  const float* arow = align + b * T_ + t0;
  float a0 = 0.f, a1 = 0.f;
#pragma unroll 8
  for (int t = 0; t < 128; ++t) {
    float a = arow[t];  // wave-uniform -> scalar load
    float2 m = *(const float2*)(mrow + (size_t)t * E_);
    a0 = fmaf(a, m.x, a0);
    a1 = fmaf(a, m.y, a1);
  }
  *(float2*)(partials + ((size_t)(b * 16 + ch)) * E_ + tid * 2) = make_float2(a0, a1);
}

__global__ __launch_bounds__(256) void ctx_reduce_kernel(
    const float* __restrict__ partials, float* __restrict__ ctx) {
  const int b = blockIdx.x, tid = threadIdx.x;
#pragma unroll
  for (int e = tid; e < E_; e += 256) {
    float s = 0.f;
#pragma unroll
    for (int c = 0; c < 16; ++c) s += partials[((size_t)(b * 16 + c)) * E_ + e];
    ctx[b * E_ + e] = s;
  }
}

// ---------------- launch ----------------
extern "C" void kernel_launch(void* const* d_in, const int* in_sizes, int n_in,
                              void* d_out, int out_size, void* d_ws, size_t ws_size,
                              hipStream_t stream) {
  (void)in_sizes; (void)n_in; (void)out_size; (void)ws_size;
  const float* queries = (const float*)d_in[0];
  const float* prev    = (const float*)d_in[1];
  const float* memory  = (const float*)d_in[2];
  const float* W_q     = (const float*)d_in[3];
  const float* W_k     = (const float*)d_in[4];
  const float* v       = (const float*)d_in[5];

  float* out = (float*)d_out;
  float* ctx_out = out;              // [N,E]
  float* align_out = out + N_ * E_;  // [N,T]

  // ws layout (floats), with lifetime-based overlap (peak 262144 floats = 1 MiB):
  //   pq_part   [0      .. 131072)   dead after projq_reduce
  //   p_choose  [131072 .. 196608)   dead after scan
  //   proj_q    [196608 .. 204800)   dead after score
  //   ctx_parts [0      .. 262144)   live only after scan
  float* ws = (float*)d_ws;
  float* pq_part   = ws;
  float* p_choose  = ws + 131072;
  float* proj_q    = ws + 196608;
  float* ctx_parts = ws;

  projq_partial_kernel<<<dim3(16, N_), 256, 0, stream>>>(queries, W_q, pq_part);
  projq_reduce_kernel<<<dim3(N_), 256, 0, stream>>>(pq_part, proj_q);
  score_kernel<<<dim3(T_ / TT, N_), 256, 0, stream>>>(memory, W_k, proj_q, v, p_choose);
  scan_kernel<<<dim3(N_), 256, 0, stream>>>(p_choose, prev, align_out);
  ctx_partial_kernel<<<dim3(16, N_), 256, 0, stream>>>(memory, align_out, ctx_parts);
  ctx_reduce_kernel<<<dim3(N_), 256, 0, stream>>>(ctx_parts, ctx_out);
}

// Round 3
// 350.940 us; speedup vs baseline: 2.7896x; 1.3283x over previous
//
#include <hip/hip_runtime.h>
#include <math.h>

#define N_ 32
#define T_ 2048
#define E_ 512
#define D_ 1024
#define U_ 256

typedef __attribute__((ext_vector_type(8))) short bf16x8;
typedef __attribute__((ext_vector_type(16))) float f32x16;

__device__ __forceinline__ short f2bf_rne(float x) {
  unsigned int u = __float_as_uint(x);
  unsigned int r = u + 0x7FFFu + ((u >> 16) & 1u);
  return (short)(r >> 16);
}
__device__ __forceinline__ float bf2f(short h) {
  return __uint_as_float(((unsigned int)(unsigned short)h) << 16);
}

// ---------------- kernel A: W_k -> transposed bf16 hi/lo planes [u][e] ----------------
__global__ __launch_bounds__(256) void wk_convert_kernel(
    const float* __restrict__ Wk, short* __restrict__ whi, short* __restrict__ wlo) {
  const int u = blockIdx.x;       // 0..255
  const int e = threadIdx.x;      // 0..255 (handles e, e+256)
#pragma unroll
  for (int k = 0; k < 2; ++k) {
    const int ee = e + k * 256;
    float x = Wk[(size_t)ee * U_ + u];
    short h = f2bf_rne(x);
    short l = f2bf_rne(x - bf2f(h));
    whi[u * E_ + ee] = h;
    wlo[u * E_ + ee] = l;
  }
}

// ---------------- kernel B: proj_q = queries @ W_q ----------------
__global__ __launch_bounds__(256) void projq_kernel(
    const float* __restrict__ queries, const float* __restrict__ W_q,
    float* __restrict__ proj_q) {
  const int b = blockIdx.x, u = threadIdx.x;
  const float* qb = queries + b * D_;
  float acc = 0.f;
#pragma unroll 8
  for (int d = 0; d < D_; ++d)
    acc = fmaf(qb[d], W_q[(size_t)d * U_ + u], acc);  // qb[d] wave-uniform
  proj_q[b * U_ + u] = acc;
}

// ---------------- kernel C: score via split-bf16 MFMA ----------------
// WG 256 thr = 4 waves. WG tile: 64 t-rows x 256 u. Wave ty: u in [ty*64, ty*64+64).
// Wave tile 64x64 = 2x2 tiles of mfma_f32_32x32x16_bf16; 3-product hi/lo split.
// A (memory) fp32->bf16 hi/lo staged in LDS (row stride 72 shorts = 144 B,
// XOR-16B swizzle on (m>>3)&3 -> conflict-free b128 frag reads).
// B (W_k) from precomputed bf16 planes in global (L2-resident, [u][e] row-major).
__global__ __launch_bounds__(256) void score_kernel(
    const float* __restrict__ memory, const short* __restrict__ whi,
    const short* __restrict__ wlo, const float* __restrict__ proj_q,
    const float* __restrict__ v, float* __restrict__ p_choose) {
  __shared__ short sAhi[64 * 72];
  __shared__ short sAlo[64 * 72];
  __shared__ float smem_w[4][64];

  const int b = blockIdx.y;
  const int t0 = blockIdx.x * 64;
  const int tid = threadIdx.x;
  const int lane = tid & 63;
  const int ty = tid >> 6;        // wave id -> u quadrant
  const int l31 = lane & 31;
  const int half = lane >> 5;

  f32x16 acc[2][2];
#pragma unroll
  for (int mt = 0; mt < 2; ++mt)
#pragma unroll
    for (int nt = 0; nt < 2; ++nt)
#pragma unroll
      for (int r = 0; r < 16; ++r) acc[mt][nt][r] = 0.f;

  // staging map: thread -> row sr (0..63), 16 cols at sc
  const int sr = tid >> 2;
  const int sc = (tid & 3) * 16;               // element col
  const int swz_w = ((sr >> 3) & 3) << 4;      // byte XOR

  for (int e0 = 0; e0 < E_; e0 += 64) {
    const float* src = memory + ((size_t)(b * T_ + t0 + sr)) * E_ + e0 + sc;
    float4 x0 = *(const float4*)(src + 0);
    float4 x1 = *(const float4*)(src + 4);
    float4 x2 = *(const float4*)(src + 8);
    float4 x3 = *(const float4*)(src + 12);
    float xs[16] = {x0.x, x0.y, x0.z, x0.w, x1.x, x1.y, x1.z, x1.w,
                    x2.x, x2.y, x2.z, x2.w, x3.x, x3.y, x3.z, x3.w};
    short hs[16], ls[16];
#pragma unroll
    for (int i = 0; i < 16; ++i) {
      short h = f2bf_rne(xs[i]);
      hs[i] = h;
      ls[i] = f2bf_rne(xs[i] - bf2f(h));
    }
    bf16x8 H0, H1, L0, L1;
#pragma unroll
    for (int i = 0; i < 8; ++i) {
      H0[i] = hs[i]; H1[i] = hs[8 + i];
      L0[i] = ls[i]; L1[i] = ls[8 + i];
    }
    __syncthreads();  // previous iteration's frag readers are done
    {
      char* bh = (char*)sAhi + sr * 144;
      char* bl = (char*)sAlo + sr * 144;
      const int c0 = (sc * 2) ^ swz_w;
      const int c1 = (sc * 2 + 16) ^ swz_w;
      *(bf16x8*)(bh + c0) = H0;
      *(bf16x8*)(bh + c1) = H1;
      *(bf16x8*)(bl + c0) = L0;
      *(bf16x8*)(bl + c1) = L1;
    }
    __syncthreads();

#pragma unroll
    for (int kc = 0; kc < 4; ++kc) {
      // B frags straight from global (L2): [u][e], 16B contiguous in e
      bf16x8 bh[2], bl[2];
#pragma unroll
      for (int nt = 0; nt < 2; ++nt) {
        const size_t uo = (size_t)(ty * 64 + nt * 32 + l31) * E_ + e0 + kc * 16 + half * 8;
        bh[nt] = *(const bf16x8*)(whi + uo);
        bl[nt] = *(const bf16x8*)(wlo + uo);
      }
      // A frags from LDS (swizzled)
      bf16x8 ah[2], al[2];
      const int kbyte = kc * 32 + half * 16;
#pragma unroll
      for (int mt = 0; mt < 2; ++mt) {
        const int m = mt * 32 + l31;
        const int off = m * 144 + (kbyte ^ (((m >> 3) & 3) << 4));
        ah[mt] = *(const bf16x8*)((const char*)sAhi + off);
        al[mt] = *(const bf16x8*)((const char*)sAlo + off);
      }
#pragma unroll
      for (int mt = 0; mt < 2; ++mt)
#pragma unroll
        for (int nt = 0; nt < 2; ++nt) {
          acc[mt][nt] = __builtin_amdgcn_mfma_f32_32x32x16_bf16(ah[mt], bh[nt], acc[mt][nt], 0, 0, 0);
          acc[mt][nt] = __builtin_amdgcn_mfma_f32_32x32x16_bf16(ah[mt], bl[nt], acc[mt][nt], 0, 0, 0);
          acc[mt][nt] = __builtin_amdgcn_mfma_f32_32x32x16_bf16(al[mt], bh[nt], acc[mt][nt], 0, 0, 0);
        }
    }
  }

  // ---- epilogue: w[t] = sum_u tanh(score + pq[u]) * v[u]; p = sigmoid(w) ----
  const int u0 = ty * 64 + l31;        // nt=0 column
  const int u1 = ty * 64 + 32 + l31;   // nt=1 column
  const float pq0 = proj_q[b * U_ + u0], pq1 = proj_q[b * U_ + u1];
  const float v0 = v[u0], v1 = v[u1];

  float rsum[32];
#pragma unroll
  for (int mt = 0; mt < 2; ++mt)
#pragma unroll
    for (int r = 0; r < 16; ++r)
      rsum[mt * 16 + r] = tanhf(acc[mt][0][r] + pq0) * v0 +
                          tanhf(acc[mt][1][r] + pq1) * v1;
  // butterfly within each 32-lane half (offsets <32 stay inside the half)
#pragma unroll
  for (int off = 1; off < 32; off <<= 1)
#pragma unroll
    for (int i = 0; i < 32; ++i) rsum[i] += __shfl_xor(rsum[i], off, 64);

  if (l31 == 0) {
#pragma unroll
    for (int mt = 0; mt < 2; ++mt)
#pragma unroll
      for (int r = 0; r < 16; ++r) {
        const int row = mt * 32 + (r & 3) + 8 * (r >> 2) + 4 * half;
        smem_w[ty][row] = rsum[mt * 16 + r];
      }
  }
  __syncthreads();
  if (tid < 64) {
    const float w = smem_w[0][tid] + smem_w[1][tid] + smem_w[2][tid] + smem_w[3][tid];
    p_choose[b * T_ + t0 + tid] = 1.0f / (1.0f + expf(-w));
  }
}

// ---------------- kernel D: monotonic-attention scan per batch row ----------------
__device__ __forceinline__ float block_incl_scan(float val, float* sbuf, int tid) {
  float x = val;
  sbuf[tid] = x;
  __syncthreads();
#pragma unroll
  for (int off = 1; off < 256; off <<= 1) {
    float t = (tid >= off) ? sbuf[tid - off] : 0.f;
    __syncthreads();
    x += t;
    sbuf[tid] = x;
    __syncthreads();
  }
  return x;
}

__global__ __launch_bounds__(256) void scan_kernel(
    const float* __restrict__ p_choose, const float* __restrict__ prev,
    float* __restrict__ align_out) {
  __shared__ float sbuf[256];
  const int b = blockIdx.x, tid = threadIdx.x;
  const int base = b * T_ + tid * 8;
  float4 p0 = *(const float4*)(p_choose + base);
  float4 p1 = *(const float4*)(p_choose + base + 4);
  float p[8] = {p0.x, p0.y, p0.z, p0.w, p1.x, p1.y, p1.z, p1.w};
  float s[8];
  float run = 0.f;
#pragma unroll
  for (int k = 0; k < 8; ++k) {
    float x = 1.0f - p[k];
    x = fminf(fmaxf(x, 1e-20f), 1.0f);
    run += logf(x);
    s[k] = run;
  }
  float incl = block_incl_scan(run, sbuf, tid);
  float excl = incl - run;
  float cp[8];
#pragma unroll
  for (int k = 0; k < 8; ++k)
    cp[k] = expf(excl + (k ? s[k - 1] : 0.f));
  float4 r0 = *(const float4*)(prev + base);
  float4 r1 = *(const float4*)(prev + base + 4);
  float pr[8] = {r0.x, r0.y, r0.z, r0.w, r1.x, r1.y, r1.z, r1.w};
  float s2[8];
  float run2 = 0.f;
#pragma unroll
  for (int k = 0; k < 8; ++k) {
    float d = fminf(fmaxf(cp[k], 1e-10f), 1.0f);
    run2 += pr[k] / d;
    s2[k] = run2;
  }
  float incl2 = block_incl_scan(run2, sbuf, tid);
  float excl2 = incl2 - run2;
#pragma unroll
  for (int k = 0; k < 8; ++k)
    p[k] = p[k] * cp[k] * (excl2 + s2[k]);
  *(float4*)(align_out + base) = make_float4(p[0], p[1], p[2], p[3]);
  *(float4*)(align_out + base + 4) = make_float4(p[4], p[5], p[6], p[7]);
}

// ---------------- kernel E/F: contexts = alignments . memory ----------------
__global__ __launch_bounds__(256) void ctx_partial_kernel(
    const float* __restrict__ memory, const float* __restrict__ align,
    float* __restrict__ partials) {
  const int b = blockIdx.y, ch = blockIdx.x, tid = threadIdx.x;
  const int tg = tid >> 7;             // 0,1
  const int col = (tid & 127) * 4;     // float4 per lane
  const int t0 = ch * 256 + tg * 128;
  const float* mrow = memory + ((size_t)(b * T_ + t0)) * E_ + col;
  const float* arow = align + b * T_ + t0;
  float4 a = make_float4(0.f, 0.f, 0.f, 0.f);
#pragma unroll 4
  for (int t = 0; t < 128; ++t) {
    float al = arow[t];  // wave-uniform -> scalar load
    float4 m = *(const float4*)(mrow + (size_t)t * E_);
    a.x = fmaf(al, m.x, a.x);
    a.y = fmaf(al, m.y, a.y);
    a.z = fmaf(al, m.z, a.z);
    a.w = fmaf(al, m.w, a.w);
  }
  *(float4*)(partials + ((size_t)(b * 16 + ch * 2 + tg)) * E_ + col) = a;
}

__global__ __launch_bounds__(256) void ctx_reduce_kernel(
    const float* __restrict__ partials, float* __restrict__ ctx) {
  const int b = blockIdx.x, tid = threadIdx.x;
#pragma unroll
  for (int e = tid; e < E_; e += 256) {
    float s = 0.f;
#pragma unroll
    for (int c = 0; c < 16; ++c) s += partials[((size_t)(b * 16 + c)) * E_ + e];
    ctx[b * E_ + e] = s;
  }
}

// ---------------- launch ----------------
extern "C" void kernel_launch(void* const* d_in, const int* in_sizes, int n_in,
                              void* d_out, int out_size, void* d_ws, size_t ws_size,
                              hipStream_t stream) {
  (void)in_sizes; (void)n_in; (void)out_size; (void)ws_size;
  const float* queries = (const float*)d_in[0];
  const float* prev    = (const float*)d_in[1];
  const float* memory  = (const float*)d_in[2];
  const float* W_q     = (const float*)d_in[3];
  const float* W_k     = (const float*)d_in[4];
  const float* v       = (const float*)d_in[5];

  float* out = (float*)d_out;
  float* ctx_out = out;              // [N,E]
  float* align_out = out + N_ * E_;  // [N,T]

  // ws layout (float slots), lifetime-overlapped; peak = 262144 floats = 1 MiB:
  //   whi      [0      .. 65536)   dead after score   (short[256*512])
  //   wlo      [65536  .. 131072)  dead after score
  //   p_choose [131072 .. 196608)  dead after scan
  //   proj_q   [196608 .. 204800)  dead after score
  //   ctx_parts[0      .. 262144)  live only after scan
  float* ws = (float*)d_ws;
  short* whi      = (short*)ws;
  short* wlo      = (short*)(ws + 65536);
  float* p_choose = ws + 131072;
  float* proj_q   = ws + 196608;
  float* ctx_parts = ws;

  wk_convert_kernel<<<dim3(U_), 256, 0, stream>>>(W_k, whi, wlo);
  projq_kernel<<<dim3(N_), 256, 0, stream>>>(queries, W_q, proj_q);
  score_kernel<<<dim3(T_ / 64, N_), 256, 0, stream>>>(memory, whi, wlo, proj_q, v, p_choose);
  scan_kernel<<<dim3(N_), 256, 0, stream>>>(p_choose, prev, align_out);
  ctx_partial_kernel<<<dim3(8, N_), 256, 0, stream>>>(memory, align_out, ctx_parts);
  ctx_reduce_kernel<<<dim3(N_), 256, 0, stream>>>(ctx_parts, ctx_out);
}

// Round 4
// 308.547 us; speedup vs baseline: 3.1729x; 1.1374x over previous
//
#include <hip/hip_runtime.h>
#include <math.h>

#define N_ 32
#define T_ 2048
#define E_ 512
#define D_ 1024
#define U_ 256
#define PQ_CH 4

typedef __attribute__((ext_vector_type(8))) short bf16x8;
typedef __attribute__((ext_vector_type(16))) float f32x16;

__device__ __forceinline__ short f2bf_rne(float x) {
  unsigned int u = __float_as_uint(x);
  unsigned int r = u + 0x7FFFu + ((u >> 16) & 1u);
  return (short)(r >> 16);
}
__device__ __forceinline__ float bf2f(short h) {
  return __uint_as_float(((unsigned int)(unsigned short)h) << 16);
}

// ---------------- kernel A: W_k -> transposed bf16 hi/lo planes [u][e] ----------------
// LDS-tiled transpose: coalesced reads over u, coalesced writes over e.
__global__ __launch_bounds__(256) void wk_convert_kernel(
    const float* __restrict__ Wk, short* __restrict__ whi, short* __restrict__ wlo) {
  __shared__ float tile[64][65];
  const int u0 = blockIdx.x * 64, e0 = blockIdx.y * 64;
  const int tid = threadIdx.x;
  const int c = tid & 63, r4 = tid >> 6;
#pragma unroll
  for (int r = 0; r < 16; ++r) {
    const int e = r * 4 + r4;
    tile[c][e] = Wk[(size_t)(e0 + e) * U_ + u0 + c];  // coalesced over u=c
  }
  __syncthreads();
#pragma unroll
  for (int r = 0; r < 16; ++r) {
    const int ul = r * 4 + r4;
    float x = tile[ul][c];
    short h = f2bf_rne(x);
    short l = f2bf_rne(x - bf2f(h));
    whi[(size_t)(u0 + ul) * E_ + e0 + c] = h;  // coalesced over e=c
    wlo[(size_t)(u0 + ul) * E_ + e0 + c] = l;
  }
}

// ---------------- kernel B: proj_q = queries @ W_q (split over d to fill CUs) ----------------
__global__ __launch_bounds__(256) void projq_partial_kernel(
    const float* __restrict__ queries, const float* __restrict__ W_q,
    float* __restrict__ pq_part) {
  const int b = blockIdx.y, ch = blockIdx.x, tid = threadIdx.x;
  const int d0 = ch * (D_ / PQ_CH);
  const float* q = queries + b * D_ + d0;
  const float* wq = W_q + (size_t)d0 * U_ + tid;
  float acc = 0.f;
#pragma unroll 8
  for (int d = 0; d < D_ / PQ_CH; ++d)
    acc = fmaf(q[d], wq[(size_t)d * U_], acc);
  pq_part[((b * PQ_CH) + ch) * U_ + tid] = acc;
}

__global__ __launch_bounds__(256) void projq_reduce_kernel(
    const float* __restrict__ pq_part, float* __restrict__ proj_q) {
  const int b = blockIdx.x, tid = threadIdx.x;
  float s = 0.f;
#pragma unroll
  for (int c = 0; c < PQ_CH; ++c) s += pq_part[((b * PQ_CH) + c) * U_ + tid];
  proj_q[b * U_ + tid] = s;
}

// ---------------- kernel C: score via split-bf16 MFMA, double-buffered LDS ----------------
// WG 256 = 4 waves; tile 64t x 256u; wave = 64x64 via 2x2 mfma_f32_32x32x16_bf16,
// 3-product hi/lo split. A staged fp32->bf16 in LDS, 128B rows, slot-XOR swizzle
// (slot ^= m&7): conflict-free for both staging b128 writes and frag b128 reads.
// Pipeline: prefetch global chunk it+1 into regs BEFORE MFMA section of chunk it;
// one barrier per iteration (write buf p^1 while others may read buf p).
__global__ __launch_bounds__(256) void score_kernel(
    const float* __restrict__ memory, const short* __restrict__ whi,
    const short* __restrict__ wlo, const float* __restrict__ proj_q,
    const float* __restrict__ v, float* __restrict__ p_choose) {
  __shared__ short sAhi[2][64 * 64];
  __shared__ short sAlo[2][64 * 64];
  __shared__ float smem_w[4][64];

  const int b = blockIdx.y;
  const int t0 = blockIdx.x * 64;
  const int tid = threadIdx.x;
  const int lane = tid & 63;
  const int ty = tid >> 6;
  const int l31 = lane & 31;
  const int half = lane >> 5;

  f32x16 acc[2][2];
#pragma unroll
  for (int mt = 0; mt < 2; ++mt)
#pragma unroll
    for (int nt = 0; nt < 2; ++nt)
#pragma unroll
      for (int r = 0; r < 16; ++r) acc[mt][nt][r] = 0.f;

  const int sr = tid >> 2;                            // staging row 0..63
  const int sc4 = tid & 3;                            // 16-elem group
  const int wslot0 = ((2 * sc4) ^ (sr & 7)) * 16;     // byte offsets in 128B row
  const int wslot1 = ((2 * sc4 + 1) ^ (sr & 7)) * 16;
  const float* srow = memory + ((size_t)(b * T_ + t0 + sr)) * E_ + sc4 * 16;

  float4 xr0, xr1, xr2, xr3;
  auto load_chunk = [&](int it) {
    const float* src = srow + it * 64;
    xr0 = *(const float4*)(src);
    xr1 = *(const float4*)(src + 4);
    xr2 = *(const float4*)(src + 8);
    xr3 = *(const float4*)(src + 12);
  };
  auto stage_chunk = [&](int p) {
    float xs[16] = {xr0.x, xr0.y, xr0.z, xr0.w, xr1.x, xr1.y, xr1.z, xr1.w,
                    xr2.x, xr2.y, xr2.z, xr2.w, xr3.x, xr3.y, xr3.z, xr3.w};
    bf16x8 H0, H1, L0, L1;
#pragma unroll
    for (int i = 0; i < 8; ++i) {
      short h = f2bf_rne(xs[i]);
      H0[i] = h;
      L0[i] = f2bf_rne(xs[i] - bf2f(h));
      short h2 = f2bf_rne(xs[8 + i]);
      H1[i] = h2;
      L1[i] = f2bf_rne(xs[8 + i] - bf2f(h2));
    }
    char* bh = (char*)&sAhi[p][0] + sr * 128;
    char* bl = (char*)&sAlo[p][0] + sr * 128;
    *(bf16x8*)(bh + wslot0) = H0;
    *(bf16x8*)(bh + wslot1) = H1;
    *(bf16x8*)(bl + wslot0) = L0;
    *(bf16x8*)(bl + wslot1) = L1;
  };

  load_chunk(0);
  stage_chunk(0);
  __syncthreads();

  for (int it = 0; it < 8; ++it) {
    const int p = it & 1;
    if (it < 7) load_chunk(it + 1);  // prefetch next chunk (no wait until stage)
    const int e0 = it * 64;
#pragma unroll
    for (int kc = 0; kc < 4; ++kc) {
      bf16x8 bh[2], bl[2];
#pragma unroll
      for (int nt = 0; nt < 2; ++nt) {
        const size_t uo = (size_t)(ty * 64 + nt * 32 + l31) * E_ + e0 + kc * 16 + half * 8;
        bh[nt] = *(const bf16x8*)(whi + uo);
        bl[nt] = *(const bf16x8*)(wlo + uo);
      }
      bf16x8 ah[2], al[2];
#pragma unroll
      for (int mt = 0; mt < 2; ++mt) {
        const int m = mt * 32 + l31;
        const int off = m * 128 + (((kc * 2 + half) ^ (m & 7)) * 16);
        ah[mt] = *(const bf16x8*)((const char*)&sAhi[p][0] + off);
        al[mt] = *(const bf16x8*)((const char*)&sAlo[p][0] + off);
      }
#pragma unroll
      for (int mt = 0; mt < 2; ++mt)
#pragma unroll
        for (int nt = 0; nt < 2; ++nt) {
          acc[mt][nt] = __builtin_amdgcn_mfma_f32_32x32x16_bf16(ah[mt], bh[nt], acc[mt][nt], 0, 0, 0);
          acc[mt][nt] = __builtin_amdgcn_mfma_f32_32x32x16_bf16(ah[mt], bl[nt], acc[mt][nt], 0, 0, 0);
          acc[mt][nt] = __builtin_amdgcn_mfma_f32_32x32x16_bf16(al[mt], bh[nt], acc[mt][nt], 0, 0, 0);
        }
    }
    if (it < 7) {
      stage_chunk(p ^ 1);  // writes the buffer nobody reads this iter
      __syncthreads();
    }
  }

  // ---- epilogue: w[t] = sum_u tanh(score + pq[u]) * v[u]; p = sigmoid(w) ----
  const int u0 = ty * 64 + l31;
  const int u1 = ty * 64 + 32 + l31;
  const float pq0 = proj_q[b * U_ + u0], pq1 = proj_q[b * U_ + u1];
  const float v0 = v[u0], v1 = v[u1];

  float rsum[32];
#pragma unroll
  for (int mt = 0; mt < 2; ++mt)
#pragma unroll
    for (int r = 0; r < 16; ++r)
      rsum[mt * 16 + r] = tanhf(acc[mt][0][r] + pq0) * v0 +
                          tanhf(acc[mt][1][r] + pq1) * v1;
#pragma unroll
  for (int off = 1; off < 32; off <<= 1)
#pragma unroll
    for (int i = 0; i < 32; ++i) rsum[i] += __shfl_xor(rsum[i], off, 64);

  __syncthreads();  // MFMA section fully done before reusing LDS region
  if (l31 == 0) {
#pragma unroll
    for (int mt = 0; mt < 2; ++mt)
#pragma unroll
      for (int r = 0; r < 16; ++r) {
        const int row = mt * 32 + (r & 3) + 8 * (r >> 2) + 4 * half;
        smem_w[ty][row] = rsum[mt * 16 + r];
      }
  }
  __syncthreads();
  if (tid < 64) {
    const float w = smem_w[0][tid] + smem_w[1][tid] + smem_w[2][tid] + smem_w[3][tid];
    p_choose[b * T_ + t0 + tid] = 1.0f / (1.0f + expf(-w));
  }
}

// ---------------- kernel D: monotonic-attention scan per batch row ----------------
__device__ __forceinline__ float block_incl_scan(float val, float* sbuf, int tid) {
  float x = val;
  sbuf[tid] = x;
  __syncthreads();
#pragma unroll
  for (int off = 1; off < 256; off <<= 1) {
    float t = (tid >= off) ? sbuf[tid - off] : 0.f;
    __syncthreads();
    x += t;
    sbuf[tid] = x;
    __syncthreads();
  }
  return x;
}

__global__ __launch_bounds__(256) void scan_kernel(
    const float* __restrict__ p_choose, const float* __restrict__ prev,
    float* __restrict__ align_out) {
  __shared__ float sbuf[256];
  const int b = blockIdx.x, tid = threadIdx.x;
  const int base = b * T_ + tid * 8;
  float4 p0 = *(const float4*)(p_choose + base);
  float4 p1 = *(const float4*)(p_choose + base + 4);
  float p[8] = {p0.x, p0.y, p0.z, p0.w, p1.x, p1.y, p1.z, p1.w};
  float s[8];
  float run = 0.f;
#pragma unroll
  for (int k = 0; k < 8; ++k) {
    float x = 1.0f - p[k];
    x = fminf(fmaxf(x, 1e-20f), 1.0f);
    run += logf(x);
    s[k] = run;
  }
  float incl = block_incl_scan(run, sbuf, tid);
  float excl = incl - run;
  float cp[8];
#pragma unroll
  for (int k = 0; k < 8; ++k)
    cp[k] = expf(excl + (k ? s[k - 1] : 0.f));
  float4 r0 = *(const float4*)(prev + base);
  float4 r1 = *(const float4*)(prev + base + 4);
  float pr[8] = {r0.x, r0.y, r0.z, r0.w, r1.x, r1.y, r1.z, r1.w};
  float s2[8];
  float run2 = 0.f;
#pragma unroll
  for (int k = 0; k < 8; ++k) {
    float d = fminf(fmaxf(cp[k], 1e-10f), 1.0f);
    run2 += pr[k] / d;
    s2[k] = run2;
  }
  float incl2 = block_incl_scan(run2, sbuf, tid);
  float excl2 = incl2 - run2;
#pragma unroll
  for (int k = 0; k < 8; ++k)
    p[k] = p[k] * cp[k] * (excl2 + s2[k]);
  *(float4*)(align_out + base) = make_float4(p[0], p[1], p[2], p[3]);
  *(float4*)(align_out + base + 4) = make_float4(p[4], p[5], p[6], p[7]);
}

// ---------------- kernel E/F: contexts = alignments . memory ----------------
__global__ __launch_bounds__(256) void ctx_partial_kernel(
    const float* __restrict__ memory, const float* __restrict__ align,
    float* __restrict__ partials) {
  const int b = blockIdx.y, ch = blockIdx.x, tid = threadIdx.x;
  const int tg = tid >> 7;
  const int col = (tid & 127) * 4;
  const int t0 = ch * 256 + tg * 128;
  const float* mrow = memory + ((size_t)(b * T_ + t0)) * E_ + col;
  const float* arow = align + b * T_ + t0;
  float4 a = make_float4(0.f, 0.f, 0.f, 0.f);
#pragma unroll 4
  for (int t = 0; t < 128; ++t) {
    float al = arow[t];  // wave-uniform -> scalar load
    float4 m = *(const float4*)(mrow + (size_t)t * E_);
    a.x = fmaf(al, m.x, a.x);
    a.y = fmaf(al, m.y, a.y);
    a.z = fmaf(al, m.z, a.z);
    a.w = fmaf(al, m.w, a.w);
  }
  *(float4*)(partials + ((size_t)(b * 16 + ch * 2 + tg)) * E_ + col) = a;
}

__global__ __launch_bounds__(256) void ctx_reduce_kernel(
    const float* __restrict__ partials, float* __restrict__ ctx) {
  const int b = blockIdx.x, tid = threadIdx.x;
#pragma unroll
  for (int e = tid; e < E_; e += 256) {
    float s = 0.f;
#pragma unroll
    for (int c = 0; c < 16; ++c) s += partials[((size_t)(b * 16 + c)) * E_ + e];
    ctx[b * E_ + e] = s;
  }
}

// ---------------- launch ----------------
extern "C" void kernel_launch(void* const* d_in, const int* in_sizes, int n_in,
                              void* d_out, int out_size, void* d_ws, size_t ws_size,
                              hipStream_t stream) {
  (void)in_sizes; (void)n_in; (void)out_size; (void)ws_size;
  const float* queries = (const float*)d_in[0];
  const float* prev    = (const float*)d_in[1];
  const float* memory  = (const float*)d_in[2];
  const float* W_q     = (const float*)d_in[3];
  const float* W_k     = (const float*)d_in[4];
  const float* v       = (const float*)d_in[5];

  float* out = (float*)d_out;
  float* ctx_out = out;              // [N,E]
  float* align_out = out + N_ * E_;  // [N,T]

  // ws layout (float slots), lifetime-overlapped; peak 262144 floats = 1 MiB:
  //   whi      [0      .. 65536)   dead after score
  //   wlo      [65536  .. 131072)  dead after score
  //   p_choose [131072 .. 196608)  dead after scan
  //   proj_q   [196608 .. 204800)  dead after score
  //   pq_part  [204800 .. 237568)  dead after projq_reduce
  //   ctx_parts[0      .. 262144)  live only after scan
  float* ws = (float*)d_ws;
  short* whi       = (short*)ws;
  short* wlo       = (short*)(ws + 65536);
  float* p_choose  = ws + 131072;
  float* proj_q    = ws + 196608;
  float* pq_part   = ws + 204800;
  float* ctx_parts = ws;

  wk_convert_kernel<<<dim3(U_ / 64, E_ / 64), 256, 0, stream>>>(W_k, whi, wlo);
  projq_partial_kernel<<<dim3(PQ_CH, N_), 256, 0, stream>>>(queries, W_q, pq_part);
  projq_reduce_kernel<<<dim3(N_), 256, 0, stream>>>(pq_part, proj_q);
  score_kernel<<<dim3(T_ / 64, N_), 256, 0, stream>>>(memory, whi, wlo, proj_q, v, p_choose);
  scan_kernel<<<dim3(N_), 256, 0, stream>>>(p_choose, prev, align_out);
  ctx_partial_kernel<<<dim3(8, N_), 256, 0, stream>>>(memory, align_out, ctx_parts);
  ctx_reduce_kernel<<<dim3(N_), 256, 0, stream>>>(ctx_parts, ctx_out);
}

// Round 5
// 286.308 us; speedup vs baseline: 3.4194x; 1.0777x over previous
//
#include <hip/hip_runtime.h>
#include <math.h>

#define N_ 32
#define T_ 2048
#define E_ 512
#define D_ 1024
#define U_ 256
#define PQ_CH 4

typedef __attribute__((ext_vector_type(8))) short bf16x8;
typedef __attribute__((ext_vector_type(16))) float f32x16;

__device__ __forceinline__ short f2bf_rne(float x) {
  unsigned int u = __float_as_uint(x);
  unsigned int r = u + 0x7FFFu + ((u >> 16) & 1u);
  return (short)(r >> 16);
}
__device__ __forceinline__ short f2bf_trunc(float x) {
  return (short)(__float_as_uint(x) >> 16);
}
__device__ __forceinline__ float bf2f(short h) {
  return __uint_as_float(((unsigned int)(unsigned short)h) << 16);
}

// ---------------- kernel A: W_k -> bf16 hi/lo planes in MFMA B-fragment order ----
// frag id f = ((c*4 + kc)*8 + ub)*64 + lane ; holds 8 shorts:
//   u = ub*32 + (lane&31), e = c*64 + kc*16 + (lane>>5)*8 + j   (j=0..7)
// In score_kernel a B-frag load is then base + lane*16B: fully coalesced 1KB.
__global__ __launch_bounds__(256) void wk_pack_kernel(
    const float* __restrict__ Wk, bf16x8* __restrict__ whiP, bf16x8* __restrict__ wloP) {
  const int fid = blockIdx.x * 256 + threadIdx.x;   // 0..16383
  const int lane = fid & 63;
  const int ub = (fid >> 6) & 7;
  const int kc = (fid >> 9) & 3;
  const int c = fid >> 11;
  const int u = ub * 32 + (lane & 31);
  const int e0 = c * 64 + kc * 16 + (lane >> 5) * 8;
  bf16x8 H, L;
#pragma unroll
  for (int j = 0; j < 8; ++j) {
    float x = Wk[(size_t)(e0 + j) * U_ + u];   // lanes&31 consecutive over u: coalesced
    short h = f2bf_trunc(x);                   // exact split: hi=trunc, lo exact-ish
    H[j] = h;
    L[j] = f2bf_rne(x - bf2f(h));
  }
  whiP[fid] = H;
  wloP[fid] = L;
}

// ---------------- kernel B: proj_q = queries @ W_q (split over d) ----------------
__global__ __launch_bounds__(256) void projq_partial_kernel(
    const float* __restrict__ queries, const float* __restrict__ W_q,
    float* __restrict__ pq_part) {
  const int b = blockIdx.y, ch = blockIdx.x, tid = threadIdx.x;
  const int d0 = ch * (D_ / PQ_CH);
  const float* q = queries + b * D_ + d0;
  const float* wq = W_q + (size_t)d0 * U_ + tid;
  float acc = 0.f;
#pragma unroll 8
  for (int d = 0; d < D_ / PQ_CH; ++d)
    acc = fmaf(q[d], wq[(size_t)d * U_], acc);
  pq_part[((b * PQ_CH) + ch) * U_ + tid] = acc;
}

__global__ __launch_bounds__(256) void projq_reduce_kernel(
    const float* __restrict__ pq_part, float* __restrict__ proj_q) {
  const int b = blockIdx.x, tid = threadIdx.x;
  float s = 0.f;
#pragma unroll
  for (int c = 0; c < PQ_CH; ++c) s += pq_part[((b * PQ_CH) + c) * U_ + tid];
  proj_q[b * U_ + tid] = s;
}

// ---------------- kernel C: score via split-bf16 MFMA ----------------
// Grid 512 WGs (T/128 x N) = exactly 2 WG/CU x 256 CU: one resident round.
// WG 256 thr = 4 waves; WG tile 128t x 256u; wave tile 128t x 64u =
// 4x2 mfma_f32_32x32x16_bf16, 3-product hi/lo split (acc[4][2] = 128 AGPRs).
// A staged fp32->bf16 hi/lo in LDS (128B rows, slot-XOR (m&7)), double-buffered.
// B frags loaded fragment-packed from global (L2-resident, coalesced lane*16B).
__global__ __launch_bounds__(256, 2) void score_kernel(
    const float* __restrict__ memory, const bf16x8* __restrict__ whiP,
    const bf16x8* __restrict__ wloP, const float* __restrict__ proj_q,
    const float* __restrict__ v, float* __restrict__ p_choose) {
  __shared__ short sAhi[2][128 * 64];   // 32 KB
  __shared__ short sAlo[2][128 * 64];   // 32 KB
  __shared__ float smem_w[4][128];      // 2 KB

  const int b = blockIdx.y;
  const int t0 = blockIdx.x * 128;
  const int tid = threadIdx.x;
  const int lane = tid & 63;
  const int ty = tid >> 6;
  const int l31 = lane & 31;
  const int half = lane >> 5;

  f32x16 acc[4][2];
#pragma unroll
  for (int mt = 0; mt < 4; ++mt)
#pragma unroll
    for (int nt = 0; nt < 2; ++nt)
#pragma unroll
      for (int r = 0; r < 16; ++r) acc[mt][nt][r] = 0.f;

  // staging: thread -> row sr (0..127), 32 elems at col cs
  const int sr = tid >> 1;
  const int cs = (tid & 1) * 32;
  const float* srow = memory + ((size_t)(b * T_ + t0 + sr)) * E_ + cs;

  float4 xr[8];
  auto load_chunk = [&](int it) {
    const float* src = srow + it * 64;
#pragma unroll
    for (int j = 0; j < 8; ++j) xr[j] = *(const float4*)(src + j * 4);
  };
  auto stage_chunk = [&](int p) {
    char* bh = (char*)&sAhi[p][0] + sr * 128;
    char* bl = (char*)&sAlo[p][0] + sr * 128;
#pragma unroll
    for (int j = 0; j < 4; ++j) {   // slot j holds 8 elems = xr[2j], xr[2j+1]
      float xs[8] = {xr[2 * j].x, xr[2 * j].y, xr[2 * j].z, xr[2 * j].w,
                     xr[2 * j + 1].x, xr[2 * j + 1].y, xr[2 * j + 1].z, xr[2 * j + 1].w};
      bf16x8 H, L;
#pragma unroll
      for (int i = 0; i < 8; ++i) {
        short h = f2bf_trunc(xs[i]);
        H[i] = h;
        L[i] = f2bf_rne(xs[i] - bf2f(h));
      }
      const int slot = (((tid & 1) * 4 + j) ^ (sr & 7)) * 16;
      *(bf16x8*)(bh + slot) = H;
      *(bf16x8*)(bl + slot) = L;
    }
  };

  load_chunk(0);
  stage_chunk(0);
  __syncthreads();

  for (int it = 0; it < 8; ++it) {
    const int p = it & 1;
    if (it < 7) load_chunk(it + 1);  // prefetch next chunk into regs
#pragma unroll
    for (int kc = 0; kc < 4; ++kc) {
      // B frags: fragment-packed, coalesced (lane*16B)
      bf16x8 bh[2], bl[2];
#pragma unroll
      for (int nt = 0; nt < 2; ++nt) {
        const int fidx = ((it * 4 + kc) * 8 + (ty * 2 + nt)) * 64 + lane;
        bh[nt] = whiP[fidx];
        bl[nt] = wloP[fidx];
      }
      // A frags from LDS (swizzled)
      bf16x8 ah[4], al[4];
#pragma unroll
      for (int mt = 0; mt < 4; ++mt) {
        const int m = mt * 32 + l31;
        const int off = m * 128 + (((kc * 2 + half) ^ (m & 7)) * 16);
        ah[mt] = *(const bf16x8*)((const char*)&sAhi[p][0] + off);
        al[mt] = *(const bf16x8*)((const char*)&sAlo[p][0] + off);
      }
#pragma unroll
      for (int mt = 0; mt < 4; ++mt)
#pragma unroll
        for (int nt = 0; nt < 2; ++nt) {
          acc[mt][nt] = __builtin_amdgcn_mfma_f32_32x32x16_bf16(ah[mt], bh[nt], acc[mt][nt], 0, 0, 0);
          acc[mt][nt] = __builtin_amdgcn_mfma_f32_32x32x16_bf16(ah[mt], bl[nt], acc[mt][nt], 0, 0, 0);
          acc[mt][nt] = __builtin_amdgcn_mfma_f32_32x32x16_bf16(al[mt], bh[nt], acc[mt][nt], 0, 0, 0);
        }
    }
    if (it < 7) {
      stage_chunk(p ^ 1);  // write the buffer nobody reads this iteration
      __syncthreads();
    }
  }

  // ---- epilogue: w[t] = sum_u tanh(score + pq[u]) * v[u]; p = sigmoid(w) ----
  const int u0 = ty * 64 + l31;
  const int u1 = ty * 64 + 32 + l31;
  const float pq0 = proj_q[b * U_ + u0], pq1 = proj_q[b * U_ + u1];
  const float v0 = v[u0], v1 = v[u1];

#pragma unroll
  for (int mt = 0; mt < 4; ++mt)
#pragma unroll
    for (int r = 0; r < 16; ++r) {
      float s = tanhf(acc[mt][0][r] + pq0) * v0 + tanhf(acc[mt][1][r] + pq1) * v1;
#pragma unroll
      for (int off = 1; off < 32; off <<= 1) s += __shfl_xor(s, off, 64);
      if (l31 == 0) {
        const int row = mt * 32 + (r & 3) + 8 * (r >> 2) + 4 * half;
        smem_w[ty][row] = s;
      }
    }
  __syncthreads();
  if (tid < 128) {
    const float w = smem_w[0][tid] + smem_w[1][tid] + smem_w[2][tid] + smem_w[3][tid];
    p_choose[b * T_ + t0 + tid] = 1.0f / (1.0f + expf(-w));
  }
}

// ---------------- kernel D: monotonic-attention scan per batch row ----------------
__device__ __forceinline__ float block_incl_scan(float val, float* sbuf, int tid) {
  float x = val;
  sbuf[tid] = x;
  __syncthreads();
#pragma unroll
  for (int off = 1; off < 256; off <<= 1) {
    float t = (tid >= off) ? sbuf[tid - off] : 0.f;
    __syncthreads();
    x += t;
    sbuf[tid] = x;
    __syncthreads();
  }
  return x;
}

__global__ __launch_bounds__(256) void scan_kernel(
    const float* __restrict__ p_choose, const float* __restrict__ prev,
    float* __restrict__ align_out) {
  __shared__ float sbuf[256];
  const int b = blockIdx.x, tid = threadIdx.x;
  const int base = b * T_ + tid * 8;
  float4 p0 = *(const float4*)(p_choose + base);
  float4 p1 = *(const float4*)(p_choose + base + 4);
  float p[8] = {p0.x, p0.y, p0.z, p0.w, p1.x, p1.y, p1.z, p1.w};
  float s[8];
  float run = 0.f;
#pragma unroll
  for (int k = 0; k < 8; ++k) {
    float x = 1.0f - p[k];
    x = fminf(fmaxf(x, 1e-20f), 1.0f);
    run += logf(x);
    s[k] = run;
  }
  float incl = block_incl_scan(run, sbuf, tid);
  float excl = incl - run;
  float cp[8];
#pragma unroll
  for (int k = 0; k < 8; ++k)
    cp[k] = expf(excl + (k ? s[k - 1] : 0.f));
  float4 r0 = *(const float4*)(prev + base);
  float4 r1 = *(const float4*)(prev + base + 4);
  float pr[8] = {r0.x, r0.y, r0.z, r0.w, r1.x, r1.y, r1.z, r1.w};
  float s2[8];
  float run2 = 0.f;
#pragma unroll
  for (int k = 0; k < 8; ++k) {
    float d = fminf(fmaxf(cp[k], 1e-10f), 1.0f);
    run2 += pr[k] / d;
    s2[k] = run2;
  }
  float incl2 = block_incl_scan(run2, sbuf, tid);
  float excl2 = incl2 - run2;
#pragma unroll
  for (int k = 0; k < 8; ++k)
    p[k] = p[k] * cp[k] * (excl2 + s2[k]);
  *(float4*)(align_out + base) = make_float4(p[0], p[1], p[2], p[3]);
  *(float4*)(align_out + base + 4) = make_float4(p[4], p[5], p[6], p[7]);
}

// ---------------- kernel E/F: contexts = alignments . memory ----------------
__global__ __launch_bounds__(256) void ctx_partial_kernel(
    const float* __restrict__ memory, const float* __restrict__ align,
    float* __restrict__ partials) {
  const int b = blockIdx.y, ch = blockIdx.x, tid = threadIdx.x;
  const int tg = tid >> 7;
  const int col = (tid & 127) * 4;
  const int t0 = ch * 256 + tg * 128;
  const float* mrow = memory + ((size_t)(b * T_ + t0)) * E_ + col;
  const float* arow = align + b * T_ + t0;
  float4 a = make_float4(0.f, 0.f, 0.f, 0.f);
#pragma unroll 4
  for (int t = 0; t < 128; ++t) {
    float al = arow[t];  // wave-uniform -> scalar load
    float4 m = *(const float4*)(mrow + (size_t)t * E_);
    a.x = fmaf(al, m.x, a.x);
    a.y = fmaf(al, m.y, a.y);
    a.z = fmaf(al, m.z, a.z);
    a.w = fmaf(al, m.w, a.w);
  }
  *(float4*)(partials + ((size_t)(b * 16 + ch * 2 + tg)) * E_ + col) = a;
}

__global__ __launch_bounds__(256) void ctx_reduce_kernel(
    const float* __restrict__ partials, float* __restrict__ ctx) {
  const int b = blockIdx.x, tid = threadIdx.x;
#pragma unroll
  for (int e = tid; e < E_; e += 256) {
    float s = 0.f;
#pragma unroll
    for (int c = 0; c < 16; ++c) s += partials[((size_t)(b * 16 + c)) * E_ + e];
    ctx[b * E_ + e] = s;
  }
}

// ---------------- launch ----------------
extern "C" void kernel_launch(void* const* d_in, const int* in_sizes, int n_in,
                              void* d_out, int out_size, void* d_ws, size_t ws_size,
                              hipStream_t stream) {
  (void)in_sizes; (void)n_in; (void)out_size; (void)ws_size;
  const float* queries = (const float*)d_in[0];
  const float* prev    = (const float*)d_in[1];
  const float* memory  = (const float*)d_in[2];
  const float* W_q     = (const float*)d_in[3];
  const float* W_k     = (const float*)d_in[4];
  const float* v       = (const float*)d_in[5];

  float* out = (float*)d_out;
  float* ctx_out = out;              // [N,E]
  float* align_out = out + N_ * E_;  // [N,T]

  // ws layout (float slots), lifetime-overlapped; peak 262144 floats = 1 MiB:
  //   whiP     [0      .. 65536)   dead after score  (256 KB packed bf16 frags)
  //   wloP     [65536  .. 131072)  dead after score
  //   p_choose [131072 .. 196608)  dead after scan
  //   proj_q   [196608 .. 204800)  dead after score
  //   pq_part  [204800 .. 237568)  dead after projq_reduce
  //   ctx_parts[0      .. 262144)  live only after scan
  float* ws = (float*)d_ws;
  bf16x8* whiP     = (bf16x8*)ws;
  bf16x8* wloP     = (bf16x8*)(ws + 65536);
  float* p_choose  = ws + 131072;
  float* proj_q    = ws + 196608;
  float* pq_part   = ws + 204800;
  float* ctx_parts = ws;

  wk_pack_kernel<<<dim3(64), 256, 0, stream>>>(W_k, whiP, wloP);
  projq_partial_kernel<<<dim3(PQ_CH, N_), 256, 0, stream>>>(queries, W_q, pq_part);
  projq_reduce_kernel<<<dim3(N_), 256, 0, stream>>>(pq_part, proj_q);
  score_kernel<<<dim3(T_ / 128, N_), 256, 0, stream>>>(memory, whiP, wloP, proj_q, v, p_choose);
  scan_kernel<<<dim3(N_), 256, 0, stream>>>(p_choose, prev, align_out);
  ctx_partial_kernel<<<dim3(8, N_), 256, 0, stream>>>(memory, align_out, ctx_parts);
  ctx_reduce_kernel<<<dim3(N_), 256, 0, stream>>>(ctx_parts, ctx_out);
}

// Round 7
// 286.087 us; speedup vs baseline: 3.4220x; 1.0008x over previous
//
#include <hip/hip_runtime.h>
#include <math.h>

#define N_ 32
#define T_ 2048
#define E_ 512
#define D_ 1024
#define U_ 256

typedef __attribute__((ext_vector_type(8))) short bf16x8;
typedef __attribute__((ext_vector_type(16))) float f32x16;

__device__ __forceinline__ short f2bf_rne(float x) {
  unsigned int u = __float_as_uint(x);
  unsigned int r = u + 0x7FFFu + ((u >> 16) & 1u);
  return (short)(r >> 16);
}
__device__ __forceinline__ short f2bf_trunc(float x) {
  return (short)(__float_as_uint(x) >> 16);
}
__device__ __forceinline__ float bf2f(short h) {
  return __uint_as_float(((unsigned int)(unsigned short)h) << 16);
}

// ---------------- K1: Wk -> bf16 hi/lo B-fragments (WGs 0..63)
//                 + proj_q partials (WGs 64..95) ----------------
// frag f = ((c*4+kc)*8+ub)*64+lane : u = ub*32+(lane&31), e = c*64+kc*16+(lane>>5)*8+j
__global__ __launch_bounds__(256) void prep_kernel(
    const float* __restrict__ Wk, const float* __restrict__ queries,
    const float* __restrict__ Wq, bf16x8* __restrict__ whiP,
    bf16x8* __restrict__ wloP, float* __restrict__ pq_part) {
  const int wg = blockIdx.x, tid = threadIdx.x;
  if (wg < 64) {
    const int fid = wg * 256 + tid;
    const int lane = fid & 63;
    const int ub = (fid >> 6) & 7;
    const int kc = (fid >> 9) & 3;
    const int c = fid >> 11;
    const int u = ub * 32 + (lane & 31);
    const int e0 = c * 64 + kc * 16 + (lane >> 5) * 8;
    bf16x8 H, L;
#pragma unroll
    for (int j = 0; j < 8; ++j) {
      float x = Wk[(size_t)(e0 + j) * U_ + u];   // lanes&31 consecutive over u
      short h = f2bf_trunc(x);
      H[j] = h;
      L[j] = f2bf_rne(x - bf2f(h));
    }
    whiP[fid] = H;
    wloP[fid] = L;
  } else {
    const int id = wg - 64;          // 0..31
    const int ch = id & 3;
    const int b = id >> 2;           // 0..7?? need b 0..31 -> use 128 WGs
    // (handled by grid: see launch — 64 + 128 WGs)
    const int bb = (wg - 64) >> 2;
    const int d0 = ch * 256;
    const float* q = queries + bb * D_ + d0;
    const float* wq = Wq + (size_t)d0 * U_ + tid;
    float acc = 0.f;
#pragma unroll 8
    for (int d = 0; d < 256; ++d)
      acc = fmaf(q[d], wq[(size_t)d * U_], acc);   // q[d] wave-uniform
    pq_part[(bb * 4 + ch) * U_ + tid] = acc;
    (void)b;
  }
}

// ---------------- K2: score via split-bf16 MFMA ----------------
// Grid 512 (T/128 x N); WG 256 = 4 waves; WG tile 128t x 256u; wave 128t x 64u
// = 4x2 mfma_f32_32x32x16_bf16, 3-product hi/lo split (acc[4][2] = 128 AGPRs).
// A staged fp32->bf16 in LDS (128B rows, slot-XOR (m&7)), single-buffered
// (R4 showed dbuf neutral). B frags fragment-packed from global (L2-resident).
// Epilogue folds the pq_part 4-way reduce (saves a dispatch).
__global__ __launch_bounds__(256, 2) void score_kernel(
    const float* __restrict__ memory, const bf16x8* __restrict__ whiP,
    const bf16x8* __restrict__ wloP, const float* __restrict__ pq_part,
    const float* __restrict__ v, float* __restrict__ p_choose) {
  __shared__ short sAhi[128 * 64];   // 16 KB
  __shared__ short sAlo[128 * 64];   // 16 KB
  __shared__ float smem_w[4][128];   // 2 KB

  const int b = blockIdx.y;
  const int t0 = blockIdx.x * 128;
  const int tid = threadIdx.x;
  const int lane = tid & 63;
  const int ty = tid >> 6;
  const int l31 = lane & 31;
  const int half = lane >> 5;

  f32x16 acc[4][2];
#pragma unroll
  for (int mt = 0; mt < 4; ++mt)
#pragma unroll
    for (int nt = 0; nt < 2; ++nt)
#pragma unroll
      for (int r = 0; r < 16; ++r) acc[mt][nt][r] = 0.f;

  const int sr = tid >> 1;
  const int cs = (tid & 1) * 32;
  const float* srow = memory + ((size_t)(b * T_ + t0 + sr)) * E_ + cs;

  for (int it = 0; it < 8; ++it) {
    float4 xr[8];
    const float* src = srow + it * 64;
#pragma unroll
    for (int j = 0; j < 8; ++j) xr[j] = *(const float4*)(src + j * 4);
    __syncthreads();   // previous iteration's frag readers done
    {
      char* bhp = (char*)sAhi + sr * 128;
      char* blp = (char*)sAlo + sr * 128;
#pragma unroll
      for (int j = 0; j < 4; ++j) {
        float xs[8] = {xr[2 * j].x, xr[2 * j].y, xr[2 * j].z, xr[2 * j].w,
                       xr[2 * j + 1].x, xr[2 * j + 1].y, xr[2 * j + 1].z, xr[2 * j + 1].w};
        bf16x8 H, L;
#pragma unroll
        for (int i = 0; i < 8; ++i) {
          short h = f2bf_trunc(xs[i]);
          H[i] = h;
          L[i] = f2bf_rne(xs[i] - bf2f(h));
        }
        const int slot = (((tid & 1) * 4 + j) ^ (sr & 7)) * 16;
        *(bf16x8*)(bhp + slot) = H;
        *(bf16x8*)(blp + slot) = L;
      }
    }
    __syncthreads();

#pragma unroll
    for (int kc = 0; kc < 4; ++kc) {
      bf16x8 bh[2], bl[2];
#pragma unroll
      for (int nt = 0; nt < 2; ++nt) {
        const int fidx = ((it * 4 + kc) * 8 + (ty * 2 + nt)) * 64 + lane;
        bh[nt] = whiP[fidx];
        bl[nt] = wloP[fidx];
      }
      bf16x8 ah[4], al[4];
#pragma unroll
      for (int mt = 0; mt < 4; ++mt) {
        const int m = mt * 32 + l31;
        const int off = m * 128 + (((kc * 2 + half) ^ (m & 7)) * 16);
        ah[mt] = *(const bf16x8*)((const char*)sAhi + off);
        al[mt] = *(const bf16x8*)((const char*)sAlo + off);
      }
#pragma unroll
      for (int mt = 0; mt < 4; ++mt)
#pragma unroll
        for (int nt = 0; nt < 2; ++nt) {
          acc[mt][nt] = __builtin_amdgcn_mfma_f32_32x32x16_bf16(ah[mt], bh[nt], acc[mt][nt], 0, 0, 0);
          acc[mt][nt] = __builtin_amdgcn_mfma_f32_32x32x16_bf16(ah[mt], bl[nt], acc[mt][nt], 0, 0, 0);
          acc[mt][nt] = __builtin_amdgcn_mfma_f32_32x32x16_bf16(al[mt], bh[nt], acc[mt][nt], 0, 0, 0);
        }
    }
  }

  // epilogue: w[t] = sum_u tanh(score + pq[u]) * v[u]; p = sigmoid(w)
  const int u0 = ty * 64 + l31;
  const int u1 = u0 + 32;
  float pq0 = 0.f, pq1 = 0.f;
#pragma unroll
  for (int c = 0; c < 4; ++c) {
    pq0 += pq_part[(b * 4 + c) * U_ + u0];
    pq1 += pq_part[(b * 4 + c) * U_ + u1];
  }
  const float v0 = v[u0], v1 = v[u1];
#pragma unroll
  for (int mt = 0; mt < 4; ++mt)
#pragma unroll
    for (int r = 0; r < 16; ++r) {
      float s = tanhf(acc[mt][0][r] + pq0) * v0 + tanhf(acc[mt][1][r] + pq1) * v1;
#pragma unroll
      for (int off = 1; off < 32; off <<= 1) s += __shfl_xor(s, off, 64);
      if (l31 == 0) {
        const int row = mt * 32 + (r & 3) + 8 * (r >> 2) + 4 * half;
        smem_w[ty][row] = s;
      }
    }
  __syncthreads();
  if (tid < 128) {
    const float w = smem_w[0][tid] + smem_w[1][tid] + smem_w[2][tid] + smem_w[3][tid];
    p_choose[b * T_ + t0 + tid] = 1.0f / (1.0f + expf(-w));
  }
}

// ---------------- K3: monotonic scan per batch row + zero ctx_out ----------------
__device__ __forceinline__ float block_incl_scan(float val, float* sbuf, int tid) {
  float x = val;
  sbuf[tid] = x;
  __syncthreads();
#pragma unroll
  for (int off = 1; off < 256; off <<= 1) {
    float t = (tid >= off) ? sbuf[tid - off] : 0.f;
    __syncthreads();
    x += t;
    sbuf[tid] = x;
    __syncthreads();
  }
  return x;
}

__global__ __launch_bounds__(256) void scan_kernel(
    const float* __restrict__ p_choose, const float* __restrict__ prev,
    float* __restrict__ align_out, float* __restrict__ ctx_out) {
  __shared__ float sbuf[256];
  const int b = blockIdx.x, tid = threadIdx.x;
  // zero this batch's ctx row (d_out is poisoned before every call)
  ctx_out[b * E_ + tid] = 0.f;
  ctx_out[b * E_ + 256 + tid] = 0.f;
  const int base = b * T_ + tid * 8;
  float4 p0 = *(const float4*)(p_choose + base);
  float4 p1 = *(const float4*)(p_choose + base + 4);
  float p[8] = {p0.x, p0.y, p0.z, p0.w, p1.x, p1.y, p1.z, p1.w};
  float s[8];
  float run = 0.f;
#pragma unroll
  for (int k = 0; k < 8; ++k) {
    float x = 1.0f - p[k];
    x = fminf(fmaxf(x, 1e-20f), 1.0f);
    run += logf(x);
    s[k] = run;
  }
  float incl = block_incl_scan(run, sbuf, tid);
  float excl = incl - run;
  float cp[8];
#pragma unroll
  for (int k = 0; k < 8; ++k)
    cp[k] = expf(excl + (k ? s[k - 1] : 0.f));
  float4 r0 = *(const float4*)(prev + base);
  float4 r1 = *(const float4*)(prev + base + 4);
  float pr[8] = {r0.x, r0.y, r0.z, r0.w, r1.x, r1.y, r1.z, r1.w};
  float s2[8];
  float run2 = 0.f;
#pragma unroll
  for (int k = 0; k < 8; ++k) {
    float d = fminf(fmaxf(cp[k], 1e-10f), 1.0f);
    run2 += pr[k] / d;
    s2[k] = run2;
  }
  float incl2 = block_incl_scan(run2, sbuf, tid);
  float excl2 = incl2 - run2;
#pragma unroll
  for (int k = 0; k < 8; ++k)
    p[k] = p[k] * cp[k] * (excl2 + s2[k]);
  *(float4*)(align_out + base) = make_float4(p[0], p[1], p[2], p[3]);
  *(float4*)(align_out + base + 4) = make_float4(p[4], p[5], p[6], p[7]);
}

// ---------------- K4: contexts = alignments . memory (atomic accumulate) ----------
// 512 WGs: wg -> (b, 128-row chunk); each half-WG does 64 rows x full E.
// 32 atomicAdds per output address — negligible contention.
__global__ __launch_bounds__(256) void ctx_kernel(
    const float* __restrict__ memory, const float* __restrict__ align,
    float* __restrict__ ctx_out) {
  const int wg = blockIdx.x, tid = threadIdx.x;
  const int b = wg >> 4;
  const int t0 = (wg & 15) * 128 + (tid >> 7) * 64;
  const int col = (tid & 127) * 4;
  const float* mrow = memory + ((size_t)(b * T_ + t0)) * E_ + col;
  const float* arow = align + b * T_ + t0;
  float4 a = make_float4(0.f, 0.f, 0.f, 0.f);
#pragma unroll 4
  for (int t = 0; t < 64; ++t) {
    float al = arow[t];   // wave-uniform -> scalar load
    float4 m = *(const float4*)(mrow + (size_t)t * E_);
    a.x = fmaf(al, m.x, a.x);
    a.y = fmaf(al, m.y, a.y);
    a.z = fmaf(al, m.z, a.z);
    a.w = fmaf(al, m.w, a.w);
  }
  float* dst = ctx_out + b * E_ + col;
  atomicAdd(dst + 0, a.x);
  atomicAdd(dst + 1, a.y);
  atomicAdd(dst + 2, a.z);
  atomicAdd(dst + 3, a.w);
}

// ---------------- launch ----------------
extern "C" void kernel_launch(void* const* d_in, const int* in_sizes, int n_in,
                              void* d_out, int out_size, void* d_ws, size_t ws_size,
                              hipStream_t stream) {
  (void)in_sizes; (void)n_in; (void)out_size; (void)ws_size;
  const float* queries = (const float*)d_in[0];
  const float* prev    = (const float*)d_in[1];
  const float* memory  = (const float*)d_in[2];
  const float* Wq      = (const float*)d_in[3];
  const float* Wk      = (const float*)d_in[4];
  const float* v       = (const float*)d_in[5];

  float* out = (float*)d_out;
  float* ctx_out = out;              // [N,E]
  float* align_out = out + N_ * E_;  // [N,T]

  // ws layout (float slots): whiP [0,65536)  wloP [65536,131072)
  //   p_choose [131072,196608)  pq_part [196608,200704)
  float* ws = (float*)d_ws;
  bf16x8* whiP    = (bf16x8*)ws;
  bf16x8* wloP    = (bf16x8*)(ws + 65536);
  float* p_choose = ws + 131072;
  float* pq_part  = ws + 196608;

  prep_kernel<<<dim3(64 + 128), 256, 0, stream>>>(Wk, queries, Wq, whiP, wloP, pq_part);
  score_kernel<<<dim3(T_ / 128, N_), 256, 0, stream>>>(memory, whiP, wloP, pq_part, v, p_choose);
  scan_kernel<<<dim3(N_), 256, 0, stream>>>(p_choose, prev, align_out, ctx_out);
  ctx_kernel<<<dim3(512), 256, 0, stream>>>(memory, align_out, ctx_out);
}

// Round 8
// 279.469 us; speedup vs baseline: 3.5030x; 1.0237x over previous
//
#include <hip/hip_runtime.h>
#include <math.h>

#define N_ 32
#define T_ 2048
#define E_ 512
#define D_ 1024
#define U_ 256

typedef __attribute__((ext_vector_type(8))) short bf16x8;
typedef __attribute__((ext_vector_type(16))) float f32x16;

__device__ __forceinline__ short f2bf_rne(float x) {
  unsigned int u = __float_as_uint(x);
  unsigned int r = u + 0x7FFFu + ((u >> 16) & 1u);
  return (short)(r >> 16);
}
__device__ __forceinline__ short f2bf_trunc(float x) {
  return (short)(__float_as_uint(x) >> 16);
}
__device__ __forceinline__ float bf2f(short h) {
  return __uint_as_float(((unsigned int)(unsigned short)h) << 16);
}
// tanh via hw exp2+rcp: tanh(x) = 1 - 2/(e^{2x}+1); saturates correctly at +-inf
__device__ __forceinline__ float fast_tanh(float x) {
  float t = exp2f(x * 2.8853900817779268f);   // e^{2x}, v_exp_f32
  return 1.0f - 2.0f * __builtin_amdgcn_rcpf(t + 1.0f);
}
__device__ __forceinline__ float fast_sigmoid(float w) {
  return __builtin_amdgcn_rcpf(1.0f + exp2f(-1.4426950408889634f * w));
}

// ---------------- K1: Wk -> bf16 hi/lo B-fragments (WGs 0..63)
//                 + proj_q partials (WGs 64..191) ----------------
// frag f = ((c*4+kc)*8+ub)*64+lane : u = ub*32+(lane&31), e = c*64+kc*16+(lane>>5)*8+j
__global__ __launch_bounds__(256) void prep_kernel(
    const float* __restrict__ Wk, const float* __restrict__ queries,
    const float* __restrict__ Wq, bf16x8* __restrict__ whiP,
    bf16x8* __restrict__ wloP, float* __restrict__ pq_part) {
  const int wg = blockIdx.x, tid = threadIdx.x;
  if (wg < 64) {
    const int fid = wg * 256 + tid;
    const int lane = fid & 63;
    const int ub = (fid >> 6) & 7;
    const int kc = (fid >> 9) & 3;
    const int c = fid >> 11;
    const int u = ub * 32 + (lane & 31);
    const int e0 = c * 64 + kc * 16 + (lane >> 5) * 8;
    bf16x8 H, L;
#pragma unroll
    for (int j = 0; j < 8; ++j) {
      float x = Wk[(size_t)(e0 + j) * U_ + u];   // lanes&31 consecutive over u
      short h = f2bf_trunc(x);
      H[j] = h;
      L[j] = f2bf_rne(x - bf2f(h));
    }
    whiP[fid] = H;
    wloP[fid] = L;
  } else {
    const int ch = (wg - 64) & 3;
    const int bb = (wg - 64) >> 2;
    const int d0 = ch * 256;
    const float* q = queries + bb * D_ + d0;
    const float* wq = Wq + (size_t)d0 * U_ + tid;
    float acc = 0.f;
#pragma unroll 8
    for (int d = 0; d < 256; ++d)
      acc = fmaf(q[d], wq[(size_t)d * U_], acc);   // q[d] wave-uniform
    pq_part[(bb * 4 + ch) * U_ + tid] = acc;
  }
}

// ---------------- K2: score via split-bf16 MFMA ----------------
// Grid 512 (T/128 x N); WG 256 = 4 waves; WG tile 128t x 256u; wave 128t x 64u
// = 4x2 mfma_f32_32x32x16_bf16, 3-product hi/lo split (acc[4][2] = 128 AGPRs).
// A staged fp32->bf16 in LDS (128B rows, slot-XOR (m&7)), single-buffered.
// B frags fragment-packed from global (L2-resident). Epilogue folds the
// pq_part 4-way reduce; transcendentals via hw exp2/rcp (libm tanhf is
// ~25 VALU ops x 128 calls/thread — a hidden multi-us sink).
__global__ __launch_bounds__(256, 2) void score_kernel(
    const float* __restrict__ memory, const bf16x8* __restrict__ whiP,
    const bf16x8* __restrict__ wloP, const float* __restrict__ pq_part,
    const float* __restrict__ v, float* __restrict__ p_choose) {
  __shared__ short sAhi[128 * 64];   // 16 KB
  __shared__ short sAlo[128 * 64];   // 16 KB
  __shared__ float smem_w[4][128];   // 2 KB

  const int b = blockIdx.y;
  const int t0 = blockIdx.x * 128;
  const int tid = threadIdx.x;
  const int lane = tid & 63;
  const int ty = tid >> 6;
  const int l31 = lane & 31;
  const int half = lane >> 5;

  f32x16 acc[4][2];
#pragma unroll
  for (int mt = 0; mt < 4; ++mt)
#pragma unroll
    for (int nt = 0; nt < 2; ++nt)
#pragma unroll
      for (int r = 0; r < 16; ++r) acc[mt][nt][r] = 0.f;

  const int sr = tid >> 1;
  const int cs = (tid & 1) * 32;
  const float* srow = memory + ((size_t)(b * T_ + t0 + sr)) * E_ + cs;

  for (int it = 0; it < 8; ++it) {
    float4 xr[8];
    const float* src = srow + it * 64;
#pragma unroll
    for (int j = 0; j < 8; ++j) xr[j] = *(const float4*)(src + j * 4);
    __syncthreads();   // previous iteration's frag readers done
    {
      char* bhp = (char*)sAhi + sr * 128;
      char* blp = (char*)sAlo + sr * 128;
#pragma unroll
      for (int j = 0; j < 4; ++j) {
        float xs[8] = {xr[2 * j].x, xr[2 * j].y, xr[2 * j].z, xr[2 * j].w,
                       xr[2 * j + 1].x, xr[2 * j + 1].y, xr[2 * j + 1].z, xr[2 * j + 1].w};
        bf16x8 H, L;
#pragma unroll
        for (int i = 0; i < 8; ++i) {
          short h = f2bf_trunc(xs[i]);
          H[i] = h;
          L[i] = f2bf_rne(xs[i] - bf2f(h));
        }
        const int slot = (((tid & 1) * 4 + j) ^ (sr & 7)) * 16;
        *(bf16x8*)(bhp + slot) = H;
        *(bf16x8*)(blp + slot) = L;
      }
    }
    __syncthreads();

#pragma unroll
    for (int kc = 0; kc < 4; ++kc) {
      bf16x8 bh[2], bl[2];
#pragma unroll
      for (int nt = 0; nt < 2; ++nt) {
        const int fidx = ((it * 4 + kc) * 8 + (ty * 2 + nt)) * 64 + lane;
        bh[nt] = whiP[fidx];
        bl[nt] = wloP[fidx];
      }
      bf16x8 ah[4], al[4];
#pragma unroll
      for (int mt = 0; mt < 4; ++mt) {
        const int m = mt * 32 + l31;
        const int off = m * 128 + (((kc * 2 + half) ^ (m & 7)) * 16);
        ah[mt] = *(const bf16x8*)((const char*)sAhi + off);
        al[mt] = *(const bf16x8*)((const char*)sAlo + off);
      }
#pragma unroll
      for (int mt = 0; mt < 4; ++mt)
#pragma unroll
        for (int nt = 0; nt < 2; ++nt) {
          acc[mt][nt] = __builtin_amdgcn_mfma_f32_32x32x16_bf16(ah[mt], bh[nt], acc[mt][nt], 0, 0, 0);
          acc[mt][nt] = __builtin_amdgcn_mfma_f32_32x32x16_bf16(ah[mt], bl[nt], acc[mt][nt], 0, 0, 0);
          acc[mt][nt] = __builtin_amdgcn_mfma_f32_32x32x16_bf16(al[mt], bh[nt], acc[mt][nt], 0, 0, 0);
        }
    }
  }

  // epilogue: w[t] = sum_u tanh(score + pq[u]) * v[u]; p = sigmoid(w)
  const int u0 = ty * 64 + l31;
  const int u1 = u0 + 32;
  float pq0 = 0.f, pq1 = 0.f;
#pragma unroll
  for (int c = 0; c < 4; ++c) {
    pq0 += pq_part[(b * 4 + c) * U_ + u0];
    pq1 += pq_part[(b * 4 + c) * U_ + u1];
  }
  const float v0 = v[u0], v1 = v[u1];
#pragma unroll
  for (int mt = 0; mt < 4; ++mt)
#pragma unroll
    for (int r = 0; r < 16; ++r) {
      float s = fast_tanh(acc[mt][0][r] + pq0) * v0 + fast_tanh(acc[mt][1][r] + pq1) * v1;
#pragma unroll
      for (int off = 1; off < 32; off <<= 1) s += __shfl_xor(s, off, 64);
      if (l31 == 0) {
        const int row = mt * 32 + (r & 3) + 8 * (r >> 2) + 4 * half;
        smem_w[ty][row] = s;
      }
    }
  __syncthreads();
  if (tid < 128) {
    const float w = smem_w[0][tid] + smem_w[1][tid] + smem_w[2][tid] + smem_w[3][tid];
    p_choose[b * T_ + t0 + tid] = fast_sigmoid(w);
  }
}

// ---------------- K3: monotonic scan per batch row + zero ctx_out ----------------
__device__ __forceinline__ float block_incl_scan(float val, float* sbuf, int tid) {
  float x = val;
  sbuf[tid] = x;
  __syncthreads();
#pragma unroll
  for (int off = 1; off < 256; off <<= 1) {
    float t = (tid >= off) ? sbuf[tid - off] : 0.f;
    __syncthreads();
    x += t;
    sbuf[tid] = x;
    __syncthreads();
  }
  return x;
}

__global__ __launch_bounds__(256) void scan_kernel(
    const float* __restrict__ p_choose, const float* __restrict__ prev,
    float* __restrict__ align_out, float* __restrict__ ctx_out) {
  __shared__ float sbuf[256];
  const int b = blockIdx.x, tid = threadIdx.x;
  // zero this batch's ctx row (d_out is poisoned before every call)
  ctx_out[b * E_ + tid] = 0.f;
  ctx_out[b * E_ + 256 + tid] = 0.f;
  const int base = b * T_ + tid * 8;
  float4 p0 = *(const float4*)(p_choose + base);
  float4 p1 = *(const float4*)(p_choose + base + 4);
  float p[8] = {p0.x, p0.y, p0.z, p0.w, p1.x, p1.y, p1.z, p1.w};
  float s[8];
  float run = 0.f;
#pragma unroll
  for (int k = 0; k < 8; ++k) {
    float x = 1.0f - p[k];
    x = fminf(fmaxf(x, 1e-20f), 1.0f);
    run += logf(x);
    s[k] = run;
  }
  float incl = block_incl_scan(run, sbuf, tid);
  float excl = incl - run;
  float cp[8];
#pragma unroll
  for (int k = 0; k < 8; ++k)
    cp[k] = expf(excl + (k ? s[k - 1] : 0.f));
  float4 r0 = *(const float4*)(prev + base);
  float4 r1 = *(const float4*)(prev + base + 4);
  float pr[8] = {r0.x, r0.y, r0.z, r0.w, r1.x, r1.y, r1.z, r1.w};
  float s2[8];
  float run2 = 0.f;
#pragma unroll
  for (int k = 0; k < 8; ++k) {
    float d = fminf(fmaxf(cp[k], 1e-10f), 1.0f);
    run2 += pr[k] / d;
    s2[k] = run2;
  }
  float incl2 = block_incl_scan(run2, sbuf, tid);
  float excl2 = incl2 - run2;
#pragma unroll
  for (int k = 0; k < 8; ++k)
    p[k] = p[k] * cp[k] * (excl2 + s2[k]);
  *(float4*)(align_out + base) = make_float4(p[0], p[1], p[2], p[3]);
  *(float4*)(align_out + base + 4) = make_float4(p[4], p[5], p[6], p[7]);
}

// ---------------- K4: contexts = alignments . memory (atomic accumulate) ----------
// 512 WGs: wg -> (b, 128-row chunk); each half-WG does 64 rows x full E.
// Unroll-4 with batched loads: 4 float4 + 4 align scalars in flight per thread.
__global__ __launch_bounds__(256) void ctx_kernel(
    const float* __restrict__ memory, const float* __restrict__ align,
    float* __restrict__ ctx_out) {
  const int wg = blockIdx.x, tid = threadIdx.x;
  const int b = wg >> 4;
  const int t0 = (wg & 15) * 128 + (tid >> 7) * 64;
  const int col = (tid & 127) * 4;
  const float* mrow = memory + ((size_t)(b * T_ + t0)) * E_ + col;
  const float* arow = align + b * T_ + t0;
  float4 a = make_float4(0.f, 0.f, 0.f, 0.f);
  for (int t = 0; t < 64; t += 4) {
    float4 m0 = *(const float4*)(mrow + (size_t)(t + 0) * E_);
    float4 m1 = *(const float4*)(mrow + (size_t)(t + 1) * E_);
    float4 m2 = *(const float4*)(mrow + (size_t)(t + 2) * E_);
    float4 m3 = *(const float4*)(mrow + (size_t)(t + 3) * E_);
    float a0 = arow[t], a1 = arow[t + 1], a2 = arow[t + 2], a3 = arow[t + 3];
    a.x = fmaf(a0, m0.x, a.x); a.y = fmaf(a0, m0.y, a.y);
    a.z = fmaf(a0, m0.z, a.z); a.w = fmaf(a0, m0.w, a.w);
    a.x = fmaf(a1, m1.x, a.x); a.y = fmaf(a1, m1.y, a.y);
    a.z = fmaf(a1, m1.z, a.z); a.w = fmaf(a1, m1.w, a.w);
    a.x = fmaf(a2, m2.x, a.x); a.y = fmaf(a2, m2.y, a.y);
    a.z = fmaf(a2, m2.z, a.z); a.w = fmaf(a2, m2.w, a.w);
    a.x = fmaf(a3, m3.x, a.x); a.y = fmaf(a3, m3.y, a.y);
    a.z = fmaf(a3, m3.z, a.z); a.w = fmaf(a3, m3.w, a.w);
  }
  float* dst = ctx_out + b * E_ + col;
  atomicAdd(dst + 0, a.x);
  atomicAdd(dst + 1, a.y);
  atomicAdd(dst + 2, a.z);
  atomicAdd(dst + 3, a.w);
}

// ---------------- launch ----------------
extern "C" void kernel_launch(void* const* d_in, const int* in_sizes, int n_in,
                              void* d_out, int out_size, void* d_ws, size_t ws_size,
                              hipStream_t stream) {
  (void)in_sizes; (void)n_in; (void)out_size; (void)ws_size;
  const float* queries = (const float*)d_in[0];
  const float* prev    = (const float*)d_in[1];
  const float* memory  = (const float*)d_in[2];
  const float* Wq      = (const float*)d_in[3];
  const float* Wk      = (const float*)d_in[4];
  const float* v       = (const float*)d_in[5];

  float* out = (float*)d_out;
  float* ctx_out = out;              // [N,E]
  float* align_out = out + N_ * E_;  // [N,T]

  // ws layout (float slots): whiP [0,65536)  wloP [65536,131072)
  //   p_choose [131072,196608)  pq_part [196608,200704)
  float* ws = (float*)d_ws;
  bf16x8* whiP    = (bf16x8*)ws;
  bf16x8* wloP    = (bf16x8*)(ws + 65536);
  float* p_choose = ws + 131072;
  float* pq_part  = ws + 196608;

  prep_kernel<<<dim3(64 + 128), 256, 0, stream>>>(Wk, queries, Wq, whiP, wloP, pq_part);
  score_kernel<<<dim3(T_ / 128, N_), 256, 0, stream>>>(memory, whiP, wloP, pq_part, v, p_choose);
  scan_kernel<<<dim3(N_), 256, 0, stream>>>(p_choose, prev, align_out, ctx_out);
  ctx_kernel<<<dim3(512), 256, 0, stream>>>(memory, align_out, ctx_out);
}